// Round 1
// baseline (1046.064 us; speedup 1.0000x reference)
//
#include <hip/hip_runtime.h>

// SGAT layer: support0 = x@W; attn2 = einsum(support0, a2); s = attn2+sqrt(attn2^2+1)
// z = [support0 * s ; s]  (N x 136)
// acc = scatter-add over edges: acc[rows[e]] += vals[e] * z[cols[e]]
// out = acc[:, :128] / (acc[:, 128 + head] + 1e-9) + bias

#define F 128      // F_OUT * H
#define FP 136     // F_OUT*H + H (augmented with mask cols)
#define NH 8       // heads
#define NB 8       // nodes per block in GEMM kernel

__global__ __launch_bounds__(128)
void k_gemm_attn(const float* __restrict__ x, const float* __restrict__ w,
                 const float* __restrict__ a2, float* __restrict__ z, int n)
{
    __shared__ float xs[NB][F];
    __shared__ float ps[NB][F];
    const int c = threadIdx.x;          // output column 0..127
    const int n0 = blockIdx.x * NB;

    // stage x rows for NB nodes
    #pragma unroll
    for (int nn = 0; nn < NB; ++nn) {
        int node = n0 + nn;
        xs[nn][c] = (node < n) ? x[(long)node * F + c] : 0.f;
    }
    __syncthreads();

    float acc[NB];
    #pragma unroll
    for (int nn = 0; nn < NB; ++nn) acc[nn] = 0.f;

    #pragma unroll 4
    for (int k = 0; k < F; ++k) {
        float wv = w[k * F + c];        // coalesced, L2-hot (W is 64KB)
        #pragma unroll
        for (int nn = 0; nn < NB; ++nn)
            acc[nn] = fmaf(xs[nn][k], wv, acc[nn]);
    }

    const int j = c & 7;                // head index
    const float a2v = a2[c];            // a2[i*8+j] with c = i*8+j

    #pragma unroll
    for (int nn = 0; nn < NB; ++nn) ps[nn][c] = acc[nn] * a2v;
    __syncthreads();

    float sreg[NB];
    #pragma unroll
    for (int nn = 0; nn < NB; ++nn) {
        float t = 0.f;
        #pragma unroll
        for (int ii = 0; ii < 16; ++ii) t += ps[nn][ii * 8 + j];
        sreg[nn] = t + sqrtf(t * t + 1.0f);
    }

    #pragma unroll
    for (int nn = 0; nn < NB; ++nn) {
        int node = n0 + nn;
        if (node < n) {
            z[(long)node * FP + c] = acc[nn] * sreg[nn];
            if (c < NH) z[(long)node * FP + F + c] = sreg[nn];  // mask col * s, j == c
        }
    }
}

// one thread per (edge, float4 chunk): 34 chunks of 4 floats = 136 cols
__global__ __launch_bounds__(256)
void k_spmm(const int* __restrict__ rows, const int* __restrict__ cols,
            const float* __restrict__ vals, const float* __restrict__ z,
            float* __restrict__ acc, int E)
{
    int idx = blockIdx.x * blockDim.x + threadIdx.x;   // < E*34 = 17M, fits int
    int total = E * 34;
    if (idx >= total) return;
    int e = idx / 34;
    int q = idx - e * 34;
    int r = rows[e];
    int c = cols[e];
    float v = vals[e];
    float4 zv = ((const float4*)z)[(long)c * 34 + q];
    float* dst = acc + (long)r * FP + q * 4;
    atomicAdd(dst + 0, zv.x * v);
    atomicAdd(dst + 1, zv.y * v);
    atomicAdd(dst + 2, zv.z * v);
    atomicAdd(dst + 3, zv.w * v);
}

__global__ __launch_bounds__(256)
void k_norm(const float* __restrict__ acc, const float* __restrict__ bias,
            float* __restrict__ out, int n)
{
    int idx = blockIdx.x * blockDim.x + threadIdx.x;
    if (idx >= n * F) return;
    int node = idx >> 7;
    int c = idx & 127;
    float denom = acc[(long)node * FP + F + (c & 7)] + 1e-9f;
    out[idx] = acc[(long)node * FP + c] / denom + bias[c];
}

extern "C" void kernel_launch(void* const* d_in, const int* in_sizes, int n_in,
                              void* d_out, int out_size, void* d_ws, size_t ws_size,
                              hipStream_t stream)
{
    const float* x     = (const float*)d_in[0];
    const int*   ei    = (const int*)d_in[1];
    const float* vals  = (const float*)d_in[2];
    const float* w     = (const float*)d_in[3];
    const float* bias  = (const float*)d_in[4];
    const float* a2    = (const float*)d_in[5];
    float* out = (float*)d_out;

    const int N = in_sizes[0] / F;      // 50000
    const int E = in_sizes[2];          // 500000
    const int* rows = ei;
    const int* cols = ei + E;

    float* z   = (float*)d_ws;                      // N * FP floats
    float* acc = z + (long)N * FP;                  // N * FP floats

    hipMemsetAsync(acc, 0, (size_t)N * FP * sizeof(float), stream);

    dim3 b1(128), g1((N + NB - 1) / NB);
    k_gemm_attn<<<g1, b1, 0, stream>>>(x, w, a2, z, N);

    int total = E * 34;
    dim3 b2(256), g2((total + 255) / 256);
    k_spmm<<<g2, b2, 0, stream>>>(rows, cols, vals, z, acc, E);

    dim3 b3(256), g3((N * F + 255) / 256);
    k_norm<<<g3, b3, 0, stream>>>(acc, bias, out, N);
}

// Round 2
// 273.390 us; speedup vs baseline: 3.8263x; 3.8263x over previous
//
#include <hip/hip_runtime.h>

// SGAT layer, pull-based:
//   z = [ (x@W) * s ; s ]  with s = attn2 + sqrt(attn2^2+1)   (N x 136)
//   CSR-group edges by destination row on device
//   per-row gather: row_acc = sum_e vals[e] * z[cols[e]]
//   out = row_acc[:128] / (row_acc[128+head] + 1e-9) + bias   (fused epilogue)

#define F 128      // F_OUT * H
#define FP 136     // F_OUT*H + H
#define NH 8
#define NB 8       // nodes per block in GEMM kernel
#define SCAN_T 1024

__global__ __launch_bounds__(128)
void k_gemm_attn(const float* __restrict__ x, const float* __restrict__ w,
                 const float* __restrict__ a2, float* __restrict__ z, int n)
{
    __shared__ float xs[NB][F];
    __shared__ float ps[NB][F];
    const int c = threadIdx.x;
    const int n0 = blockIdx.x * NB;

    #pragma unroll
    for (int nn = 0; nn < NB; ++nn) {
        int node = n0 + nn;
        xs[nn][c] = (node < n) ? x[(long)node * F + c] : 0.f;
    }
    __syncthreads();

    float acc[NB];
    #pragma unroll
    for (int nn = 0; nn < NB; ++nn) acc[nn] = 0.f;

    #pragma unroll 4
    for (int k = 0; k < F; ++k) {
        float wv = w[k * F + c];
        #pragma unroll
        for (int nn = 0; nn < NB; ++nn)
            acc[nn] = fmaf(xs[nn][k], wv, acc[nn]);
    }

    const int j = c & 7;
    const float a2v = a2[c];

    #pragma unroll
    for (int nn = 0; nn < NB; ++nn) ps[nn][c] = acc[nn] * a2v;
    __syncthreads();

    #pragma unroll
    for (int nn = 0; nn < NB; ++nn) {
        float t = 0.f;
        #pragma unroll
        for (int ii = 0; ii < 16; ++ii) t += ps[nn][ii * 8 + j];
        float s = t + sqrtf(t * t + 1.0f);
        int node = n0 + nn;
        if (node < n) {
            z[(long)node * FP + c] = acc[nn] * s;
            if (c < NH) z[(long)node * FP + F + c] = s;
        }
    }
}

__global__ __launch_bounds__(256)
void k_hist(const int* __restrict__ rows, int* __restrict__ cnt, int E)
{
    int e = blockIdx.x * blockDim.x + threadIdx.x;
    if (e < E) atomicAdd(&cnt[rows[e]], 1);
}

// single-block exclusive scan of cnt[0..n) -> start[], and init cursor wr[] = start[]
__global__ __launch_bounds__(SCAN_T)
void k_scan(const int* __restrict__ cnt, int* __restrict__ start,
            int* __restrict__ wr, int n)
{
    __shared__ int sums[SCAN_T];
    const int t = threadIdx.x;
    const int chunk = (n + SCAN_T - 1) / SCAN_T;
    const int lo = t * chunk;
    const int hi = min(lo + chunk, n);

    int s = 0;
    for (int i = lo; i < hi; ++i) s += cnt[i];
    sums[t] = s;
    __syncthreads();

    for (int off = 1; off < SCAN_T; off <<= 1) {
        int u = (t >= off) ? sums[t - off] : 0;
        __syncthreads();
        sums[t] += u;
        __syncthreads();
    }

    int run = (t == 0) ? 0 : sums[t - 1];
    for (int i = lo; i < hi; ++i) {
        start[i] = run;
        wr[i] = run;
        run += cnt[i];
    }
}

// scatter (col, val) into row-grouped order
__global__ __launch_bounds__(256)
void k_scatter(const int* __restrict__ rows, const int* __restrict__ cols,
               const float* __restrict__ vals, int* __restrict__ wr,
               int2* __restrict__ ce, int E)
{
    int e = blockIdx.x * blockDim.x + threadIdx.x;
    if (e >= E) return;
    int r = rows[e];
    int pos = atomicAdd(&wr[r], 1);
    ce[pos] = make_int2(cols[e], __float_as_int(vals[e]));
}

// one wave per destination row: gather + accumulate + fused normalize/bias
__global__ __launch_bounds__(256)
void k_spmm_pull(const int* __restrict__ start, const int* __restrict__ cnt,
                 const int2* __restrict__ ce, const float* __restrict__ z,
                 const float* __restrict__ bias, float* __restrict__ out, int n)
{
    const int wid  = (blockIdx.x * blockDim.x + threadIdx.x) >> 6;  // row
    const int lane = threadIdx.x & 63;
    if (wid >= n) return;

    const int s0 = start[wid];
    const int c0 = cnt[wid];

    float a0 = 0.f, a1 = 0.f, am = 0.f;
    const int mcol = F + (lane & 7);

    for (int e = s0; e < s0 + c0; ++e) {
        int2 p = ce[e];                       // wave-uniform, broadcast
        const float* base = z + (long)p.x * FP;
        float v = __int_as_float(p.y);
        a0 = fmaf(v, base[lane], a0);
        a1 = fmaf(v, base[64 + lane], a1);
        am = fmaf(v, base[mcol], am);         // all lanes: own head's mask col
    }

    float d = am + 1e-9f;
    out[(long)wid * F + lane]      = a0 / d + bias[lane];
    out[(long)wid * F + 64 + lane] = a1 / d + bias[64 + lane];
}

extern "C" void kernel_launch(void* const* d_in, const int* in_sizes, int n_in,
                              void* d_out, int out_size, void* d_ws, size_t ws_size,
                              hipStream_t stream)
{
    const float* x    = (const float*)d_in[0];
    const int*   ei   = (const int*)d_in[1];
    const float* vals = (const float*)d_in[2];
    const float* w    = (const float*)d_in[3];
    const float* bias = (const float*)d_in[4];
    const float* a2   = (const float*)d_in[5];
    float* out = (float*)d_out;

    const int N = in_sizes[0] / F;
    const int E = in_sizes[2];
    const int* rows = ei;
    const int* cols = ei + E;

    // workspace carve-up (all 256B-aligned by construction)
    char* p = (char*)d_ws;
    float* z     = (float*)p;                 p += (size_t)N * FP * sizeof(float);   // 27.2 MB
    int*   cnt   = (int*)p;                   p += ((size_t)N + 64) * sizeof(int);
    int*   start = (int*)p;                   p += ((size_t)N + 64) * sizeof(int);
    int*   wr    = (int*)p;                   p += ((size_t)N + 64) * sizeof(int);
    int2*  ce    = (int2*)p;                  // E * 8B = 4 MB

    hipMemsetAsync(cnt, 0, (size_t)N * sizeof(int), stream);

    dim3 b1(128), g1((N + NB - 1) / NB);
    k_gemm_attn<<<g1, b1, 0, stream>>>(x, w, a2, z, N);

    k_hist<<<dim3((E + 255) / 256), dim3(256), 0, stream>>>(rows, cnt, E);
    k_scan<<<dim3(1), dim3(SCAN_T), 0, stream>>>(cnt, start, wr, N);
    k_scatter<<<dim3((E + 255) / 256), dim3(256), 0, stream>>>(rows, cols, vals, wr, ce, E);

    // one wave per row, 4 rows per 256-thread block
    dim3 b5(256), g5((N + 3) / 4);
    k_spmm_pull<<<g5, b5, 0, stream>>>(start, cnt, ce, z, bias, out, N);
}

// Round 3
// 173.704 us; speedup vs baseline: 6.0221x; 1.5739x over previous
//
#include <hip/hip_runtime.h>

// SGAT layer, pull-based:
//   z = [ (x@W) * s ; s ]  with s = attn2 + sqrt(attn2^2+1)   (N x 136)
//   CSR-group edges by destination row on device (hist + hierarchical scan + scatter)
//   per-row gather: row_acc = sum_e vals[e] * z[cols[e]]
//   out = row_acc[:128] / (row_acc[128+head] + 1e-9) + bias   (fused epilogue)

#define F 128      // F_OUT * H
#define FP 136     // F_OUT*H + H
#define NH 8
#define NB 8       // nodes per block in GEMM kernel
#define SCAN_ELEMS 1024   // elements per scan block (256 threads x 4)

__global__ __launch_bounds__(128)
void k_gemm_attn(const float* __restrict__ x, const float* __restrict__ w,
                 const float* __restrict__ a2, float* __restrict__ z, int n)
{
    __shared__ float xs[NB][F];
    __shared__ float ps[NB][F];
    const int c = threadIdx.x;
    const int n0 = blockIdx.x * NB;

    #pragma unroll
    for (int nn = 0; nn < NB; ++nn) {
        int node = n0 + nn;
        xs[nn][c] = (node < n) ? x[(long)node * F + c] : 0.f;
    }
    __syncthreads();

    float acc[NB];
    #pragma unroll
    for (int nn = 0; nn < NB; ++nn) acc[nn] = 0.f;

    #pragma unroll 4
    for (int k = 0; k < F; ++k) {
        float wv = w[k * F + c];
        #pragma unroll
        for (int nn = 0; nn < NB; ++nn)
            acc[nn] = fmaf(xs[nn][k], wv, acc[nn]);
    }

    const int j = c & 7;
    const float a2v = a2[c];

    #pragma unroll
    for (int nn = 0; nn < NB; ++nn) ps[nn][c] = acc[nn] * a2v;
    __syncthreads();

    #pragma unroll
    for (int nn = 0; nn < NB; ++nn) {
        float t = 0.f;
        #pragma unroll
        for (int ii = 0; ii < 16; ++ii) t += ps[nn][ii * 8 + j];
        float s = t + sqrtf(t * t + 1.0f);
        int node = n0 + nn;
        if (node < n) {
            z[(long)node * FP + c] = acc[nn] * s;
            if (c < NH) z[(long)node * FP + F + c] = s;
        }
    }
}

__global__ __launch_bounds__(256)
void k_hist(const int* __restrict__ rows, int* __restrict__ cnt, int E)
{
    int e = blockIdx.x * blockDim.x + threadIdx.x;
    if (e < E) atomicAdd(&cnt[rows[e]], 1);
}

// ---- hierarchical exclusive scan over cnt[0..n) ----

// pass 1: per-block (1024-elem) reduce -> blockSums
__global__ __launch_bounds__(256)
void k_scan_partial(const int* __restrict__ cnt, int* __restrict__ blockSums, int n)
{
    const int t = threadIdx.x;
    const int base = blockIdx.x * SCAN_ELEMS + t * 4;
    int s = 0;
    #pragma unroll
    for (int k = 0; k < 4; ++k) {
        int i = base + k;
        if (i < n) s += cnt[i];
    }
    // wave reduce
    #pragma unroll
    for (int off = 32; off >= 1; off >>= 1) s += __shfl_down(s, off, 64);
    __shared__ int ws[4];
    if ((t & 63) == 0) ws[t >> 6] = s;
    __syncthreads();
    if (t == 0) blockSums[blockIdx.x] = ws[0] + ws[1] + ws[2] + ws[3];
}

// pass 2: single small block scans blockSums (nblk <= 256) -> blockOff (exclusive)
__global__ __launch_bounds__(256)
void k_scan_mid(const int* __restrict__ blockSums, int* __restrict__ blockOff, int nblk)
{
    __shared__ int s[256];
    const int t = threadIdx.x;
    s[t] = (t < nblk) ? blockSums[t] : 0;
    __syncthreads();
    for (int off = 1; off < 256; off <<= 1) {
        int u = (t >= off) ? s[t - off] : 0;
        __syncthreads();
        s[t] += u;
        __syncthreads();
    }
    if (t < nblk) blockOff[t] = (t == 0) ? 0 : s[t - 1];
}

// pass 3: per-block exclusive scan + block offset -> start, wr
__global__ __launch_bounds__(256)
void k_scan_final(const int* __restrict__ cnt, const int* __restrict__ blockOff,
                  int* __restrict__ start, int* __restrict__ wr, int n)
{
    const int t = threadIdx.x;
    const int lane = t & 63;
    const int wv = t >> 6;
    const int base = blockIdx.x * SCAN_ELEMS + t * 4;

    int v[4];
    int sum4 = 0;
    #pragma unroll
    for (int k = 0; k < 4; ++k) {
        int i = base + k;
        v[k] = (i < n) ? cnt[i] : 0;
        sum4 += v[k];
    }

    // wave inclusive scan of thread sums
    int incl = sum4;
    #pragma unroll
    for (int off = 1; off < 64; off <<= 1) {
        int u = __shfl_up(incl, off, 64);
        if (lane >= off) incl += u;
    }

    __shared__ int waveSums[4];
    if (lane == 63) waveSums[wv] = incl;
    __syncthreads();
    if (t == 0) {
        int r = 0;
        #pragma unroll
        for (int w2 = 0; w2 < 4; ++w2) { int tmp = waveSums[w2]; waveSums[w2] = r; r += tmp; }
    }
    __syncthreads();

    int run = blockOff[blockIdx.x] + waveSums[wv] + (incl - sum4);
    #pragma unroll
    for (int k = 0; k < 4; ++k) {
        int i = base + k;
        if (i < n) { start[i] = run; wr[i] = run; }
        run += v[k];
    }
}

// scatter (col, val) into row-grouped order
__global__ __launch_bounds__(256)
void k_scatter(const int* __restrict__ rows, const int* __restrict__ cols,
               const float* __restrict__ vals, int* __restrict__ wr,
               int2* __restrict__ ce, int E)
{
    int e = blockIdx.x * blockDim.x + threadIdx.x;
    if (e >= E) return;
    int r = rows[e];
    int pos = atomicAdd(&wr[r], 1);
    ce[pos] = make_int2(cols[e], __float_as_int(vals[e]));
}

// one wave per destination row: gather + accumulate + fused normalize/bias
__global__ __launch_bounds__(256)
void k_spmm_pull(const int* __restrict__ start, const int* __restrict__ cnt,
                 const int2* __restrict__ ce, const float* __restrict__ z,
                 const float* __restrict__ bias, float* __restrict__ out, int n)
{
    const int wid  = (blockIdx.x * blockDim.x + threadIdx.x) >> 6;  // row
    const int lane = threadIdx.x & 63;
    if (wid >= n) return;

    const int s0 = start[wid];
    const int c0 = cnt[wid];

    float a0 = 0.f, a1 = 0.f, am = 0.f;
    const int mcol = F + (lane & 7);

    for (int e = s0; e < s0 + c0; ++e) {
        int2 p = ce[e];                       // wave-uniform
        const float* base = z + (long)p.x * FP;
        float v = __int_as_float(p.y);
        a0 = fmaf(v, base[lane], a0);
        a1 = fmaf(v, base[64 + lane], a1);
        am = fmaf(v, base[mcol], am);
    }

    float d = am + 1e-9f;
    out[(long)wid * F + lane]      = a0 / d + bias[lane];
    out[(long)wid * F + 64 + lane] = a1 / d + bias[64 + lane];
}

extern "C" void kernel_launch(void* const* d_in, const int* in_sizes, int n_in,
                              void* d_out, int out_size, void* d_ws, size_t ws_size,
                              hipStream_t stream)
{
    const float* x    = (const float*)d_in[0];
    const int*   ei   = (const int*)d_in[1];
    const float* vals = (const float*)d_in[2];
    const float* w    = (const float*)d_in[3];
    const float* bias = (const float*)d_in[4];
    const float* a2   = (const float*)d_in[5];
    float* out = (float*)d_out;

    const int N = in_sizes[0] / F;
    const int E = in_sizes[2];
    const int* rows = ei;
    const int* cols = ei + E;

    const int nblk = (N + SCAN_ELEMS - 1) / SCAN_ELEMS;   // 49 for N=50000 (<=256 ok)

    char* p = (char*)d_ws;
    float* z        = (float*)p;  p += (size_t)N * FP * sizeof(float);   // 27.2 MB
    int*   cnt      = (int*)p;    p += ((size_t)N + 64) * sizeof(int);
    int*   start    = (int*)p;    p += ((size_t)N + 64) * sizeof(int);
    int*   wr       = (int*)p;    p += ((size_t)N + 64) * sizeof(int);
    int*   blockSums= (int*)p;    p += 512 * sizeof(int);
    int*   blockOff = (int*)p;    p += 512 * sizeof(int);
    int2*  ce       = (int2*)p;   // E * 8B = 4 MB

    hipMemsetAsync(cnt, 0, (size_t)N * sizeof(int), stream);

    dim3 b1(128), g1((N + NB - 1) / NB);
    k_gemm_attn<<<g1, b1, 0, stream>>>(x, w, a2, z, N);

    k_hist<<<dim3((E + 255) / 256), dim3(256), 0, stream>>>(rows, cnt, E);

    k_scan_partial<<<dim3(nblk), dim3(256), 0, stream>>>(cnt, blockSums, N);
    k_scan_mid<<<dim3(1), dim3(256), 0, stream>>>(blockSums, blockOff, nblk);
    k_scan_final<<<dim3(nblk), dim3(256), 0, stream>>>(cnt, blockOff, start, wr, N);

    k_scatter<<<dim3((E + 255) / 256), dim3(256), 0, stream>>>(rows, cols, vals, wr, ce, E);

    dim3 b5(256), g5((N + 3) / 4);
    k_spmm_pull<<<g5, b5, 0, stream>>>(start, cnt, ce, z, bias, out, N);
}

// Round 4
// 167.773 us; speedup vs baseline: 6.2350x; 1.0354x over previous
//
#include <hip/hip_runtime.h>
#include <hip/hip_bf16.h>

// SGAT layer, pull-based, bf16 z:
//   z = [ (x@W) * s ; s ]  with s = attn2 + sqrt(attn2^2+1)   (N x 136, bf16)
//   CSR-group edges by destination row on device (hist + hierarchical scan + scatter)
//   per-row gather: row_acc = sum_e vals[e] * z[cols[e]]   (fp32 accum)
//   out = row_acc[:128] / (row_acc[128+head] + 1e-9) + bias (fused epilogue)

#define F 128      // F_OUT * H
#define FP 136     // F_OUT*H + H
#define NH 8
#define NB 8       // nodes per block in GEMM kernel
#define XPAD 12    // xsT row pad: 12 words = 48 B, 16B-aligned rows
#define SCAN_ELEMS 1024

static __device__ __forceinline__ unsigned short f2bf(float f) {
    __hip_bfloat16 h = __float2bfloat16(f);   // RNE
    return *(unsigned short*)&h;
}

__global__ __launch_bounds__(128)
void k_gemm_attn(const float* __restrict__ x, const float* __restrict__ w,
                 const float* __restrict__ a2, unsigned short* __restrict__ z, int n)
{
    __shared__ float xsT[F][XPAD];   // [k][nn], 16B-aligned rows
    __shared__ float ps[NB][F];
    const int c = threadIdx.x;
    const int n0 = blockIdx.x * NB;

    #pragma unroll
    for (int nn = 0; nn < NB; ++nn) {
        int node = n0 + nn;
        xsT[c][nn] = (node < n) ? x[(long)node * F + c] : 0.f;
    }
    __syncthreads();

    float acc[NB];
    #pragma unroll
    for (int nn = 0; nn < NB; ++nn) acc[nn] = 0.f;

    #pragma unroll 4
    for (int k = 0; k < F; ++k) {
        float wv = w[k * F + c];
        float4 xa = *(const float4*)&xsT[k][0];
        float4 xb = *(const float4*)&xsT[k][4];
        acc[0] = fmaf(xa.x, wv, acc[0]);
        acc[1] = fmaf(xa.y, wv, acc[1]);
        acc[2] = fmaf(xa.z, wv, acc[2]);
        acc[3] = fmaf(xa.w, wv, acc[3]);
        acc[4] = fmaf(xb.x, wv, acc[4]);
        acc[5] = fmaf(xb.y, wv, acc[5]);
        acc[6] = fmaf(xb.z, wv, acc[6]);
        acc[7] = fmaf(xb.w, wv, acc[7]);
    }

    const int j = c & 7;
    const float a2v = a2[c];

    #pragma unroll
    for (int nn = 0; nn < NB; ++nn) ps[nn][c] = acc[nn] * a2v;
    __syncthreads();

    #pragma unroll
    for (int nn = 0; nn < NB; ++nn) {
        float t = 0.f;
        #pragma unroll
        for (int ii = 0; ii < 16; ++ii) t += ps[nn][ii * 8 + j];
        float s = t + sqrtf(t * t + 1.0f);
        int node = n0 + nn;
        if (node < n) {
            z[(long)node * FP + c] = f2bf(acc[nn] * s);
            if (c < NH) z[(long)node * FP + F + c] = f2bf(s);
        }
    }
}

__global__ __launch_bounds__(256)
void k_hist(const int* __restrict__ rows, int* __restrict__ cnt, int E)
{
    int e = blockIdx.x * blockDim.x + threadIdx.x;
    if (e < E) atomicAdd(&cnt[rows[e]], 1);
}

// ---- hierarchical exclusive scan over cnt[0..n) ----

__global__ __launch_bounds__(256)
void k_scan_partial(const int* __restrict__ cnt, int* __restrict__ blockSums, int n)
{
    const int t = threadIdx.x;
    const int base = blockIdx.x * SCAN_ELEMS + t * 4;
    int s = 0;
    #pragma unroll
    for (int k = 0; k < 4; ++k) {
        int i = base + k;
        if (i < n) s += cnt[i];
    }
    #pragma unroll
    for (int off = 32; off >= 1; off >>= 1) s += __shfl_down(s, off, 64);
    __shared__ int ws[4];
    if ((t & 63) == 0) ws[t >> 6] = s;
    __syncthreads();
    if (t == 0) blockSums[blockIdx.x] = ws[0] + ws[1] + ws[2] + ws[3];
}

__global__ __launch_bounds__(256)
void k_scan_mid(const int* __restrict__ blockSums, int* __restrict__ blockOff, int nblk)
{
    __shared__ int s[256];
    const int t = threadIdx.x;
    s[t] = (t < nblk) ? blockSums[t] : 0;
    __syncthreads();
    for (int off = 1; off < 256; off <<= 1) {
        int u = (t >= off) ? s[t - off] : 0;
        __syncthreads();
        s[t] += u;
        __syncthreads();
    }
    if (t < nblk) blockOff[t] = (t == 0) ? 0 : s[t - 1];
}

__global__ __launch_bounds__(256)
void k_scan_final(const int* __restrict__ cnt, const int* __restrict__ blockOff,
                  int* __restrict__ start, int* __restrict__ wr, int n)
{
    const int t = threadIdx.x;
    const int lane = t & 63;
    const int wv = t >> 6;
    const int base = blockIdx.x * SCAN_ELEMS + t * 4;

    int v[4];
    int sum4 = 0;
    #pragma unroll
    for (int k = 0; k < 4; ++k) {
        int i = base + k;
        v[k] = (i < n) ? cnt[i] : 0;
        sum4 += v[k];
    }

    int incl = sum4;
    #pragma unroll
    for (int off = 1; off < 64; off <<= 1) {
        int u = __shfl_up(incl, off, 64);
        if (lane >= off) incl += u;
    }

    __shared__ int waveSums[4];
    if (lane == 63) waveSums[wv] = incl;
    __syncthreads();
    if (t == 0) {
        int r = 0;
        #pragma unroll
        for (int w2 = 0; w2 < 4; ++w2) { int tmp = waveSums[w2]; waveSums[w2] = r; r += tmp; }
    }
    __syncthreads();

    int run = blockOff[blockIdx.x] + waveSums[wv] + (incl - sum4);
    #pragma unroll
    for (int k = 0; k < 4; ++k) {
        int i = base + k;
        if (i < n) { start[i] = run; wr[i] = run; }
        run += v[k];
    }
}

__global__ __launch_bounds__(256)
void k_scatter(const int* __restrict__ rows, const int* __restrict__ cols,
               const float* __restrict__ vals, int* __restrict__ wr,
               int2* __restrict__ ce, int E)
{
    int e = blockIdx.x * blockDim.x + threadIdx.x;
    if (e >= E) return;
    int r = rows[e];
    int pos = atomicAdd(&wr[r], 1);
    ce[pos] = make_int2(cols[e], __float_as_int(vals[e]));
}

// one wave per destination row; bf16 z: one dword/lane = cols (2l, 2l+1)
__global__ __launch_bounds__(256)
void k_spmm_pull(const int* __restrict__ start, const int* __restrict__ cnt,
                 const int2* __restrict__ ce, const unsigned short* __restrict__ z,
                 const float* __restrict__ bias, float* __restrict__ out, int n)
{
    const int wid  = (blockIdx.x * blockDim.x + threadIdx.x) >> 6;
    const int lane = threadIdx.x & 63;
    if (wid >= n) return;

    const int s0 = start[wid];
    const int c0 = cnt[wid];

    float a0 = 0.f, a1 = 0.f, am0 = 0.f, am1 = 0.f;
    const int moff = F + 2 * (lane & 3);   // heads (2l)&7 and (2l+1)&7, one dword

    for (int e = s0; e < s0 + c0; ++e) {
        int2 p = ce[e];                                    // wave-uniform
        const unsigned short* base = z + (long)p.x * FP;
        float v = __int_as_float(p.y);
        unsigned int d  = *(const unsigned int*)(base + 2 * lane);
        unsigned int md = *(const unsigned int*)(base + moff);
        float z0 = __uint_as_float(d << 16);
        float z1 = __uint_as_float(d & 0xFFFF0000u);
        float m0 = __uint_as_float(md << 16);
        float m1 = __uint_as_float(md & 0xFFFF0000u);
        a0  = fmaf(v, z0, a0);
        a1  = fmaf(v, z1, a1);
        am0 = fmaf(v, m0, am0);
        am1 = fmaf(v, m1, am1);
    }

    float2 bv = *(const float2*)(bias + 2 * lane);
    float2 o;
    o.x = a0 / (am0 + 1e-9f) + bv.x;
    o.y = a1 / (am1 + 1e-9f) + bv.y;
    *(float2*)(out + (long)wid * F + 2 * lane) = o;
}

extern "C" void kernel_launch(void* const* d_in, const int* in_sizes, int n_in,
                              void* d_out, int out_size, void* d_ws, size_t ws_size,
                              hipStream_t stream)
{
    const float* x    = (const float*)d_in[0];
    const int*   ei   = (const int*)d_in[1];
    const float* vals = (const float*)d_in[2];
    const float* w    = (const float*)d_in[3];
    const float* bias = (const float*)d_in[4];
    const float* a2   = (const float*)d_in[5];
    float* out = (float*)d_out;

    const int N = in_sizes[0] / F;
    const int E = in_sizes[2];
    const int* rows = ei;
    const int* cols = ei + E;

    const int nblk = (N + SCAN_ELEMS - 1) / SCAN_ELEMS;   // 49 for N=50000

    char* p = (char*)d_ws;
    unsigned short* z = (unsigned short*)p;  p += (((size_t)N * FP * sizeof(unsigned short) + 255) & ~255ull);
    int*   cnt      = (int*)p;    p += ((size_t)N + 64) * sizeof(int);
    int*   start    = (int*)p;    p += ((size_t)N + 64) * sizeof(int);
    int*   wr       = (int*)p;    p += ((size_t)N + 64) * sizeof(int);
    int*   blockSums= (int*)p;    p += 512 * sizeof(int);
    int*   blockOff = (int*)p;    p += 512 * sizeof(int);
    int2*  ce       = (int2*)p;   // E * 8B

    hipMemsetAsync(cnt, 0, (size_t)N * sizeof(int), stream);

    dim3 b1(128), g1((N + NB - 1) / NB);
    k_gemm_attn<<<g1, b1, 0, stream>>>(x, w, a2, z, N);

    k_hist<<<dim3((E + 255) / 256), dim3(256), 0, stream>>>(rows, cnt, E);

    k_scan_partial<<<dim3(nblk), dim3(256), 0, stream>>>(cnt, blockSums, N);
    k_scan_mid<<<dim3(1), dim3(256), 0, stream>>>(blockSums, blockOff, nblk);
    k_scan_final<<<dim3(nblk), dim3(256), 0, stream>>>(cnt, blockOff, start, wr, N);

    k_scatter<<<dim3((E + 255) / 256), dim3(256), 0, stream>>>(rows, cols, vals, wr, ce, E);

    dim3 b5(256), g5((N + 3) / 4);
    k_spmm_pull<<<g5, b5, 0, stream>>>(start, cnt, ce, z, bias, out, N);
}

// Round 5
// 141.134 us; speedup vs baseline: 7.4118x; 1.1888x over previous
//
#include <hip/hip_runtime.h>
#include <hip/hip_bf16.h>

// SGAT layer, pull-based, bf16 z:
//   z = [ (x@W) * s ; s ]  with s = attn2 + sqrt(attn2^2+1)   (N x 136, bf16)
//   CSR-group edges by destination row on device (hist + hierarchical scan + scatter)
//   per-row gather (4 edges in flight per wave): row_acc = sum_e vals[e] * z[cols[e]]
//   out = row_acc[:128] / (row_acc[128+head] + 1e-9) + bias (fused epilogue)

#define F 128      // F_OUT * H
#define FP 136     // F_OUT*H + H
#define NH 8
#define NB 8       // nodes per block in GEMM kernel
#define XPAD 12
#define SCAN_ELEMS 1024

static __device__ __forceinline__ unsigned short f2bf(float f) {
    __hip_bfloat16 h = __float2bfloat16(f);   // RNE
    return *(unsigned short*)&h;
}
static __device__ __forceinline__ float bf_lo(unsigned int u) { return __uint_as_float(u << 16); }
static __device__ __forceinline__ float bf_hi(unsigned int u) { return __uint_as_float(u & 0xFFFF0000u); }

__global__ __launch_bounds__(128)
void k_gemm_attn(const float* __restrict__ x, const float* __restrict__ w,
                 const float* __restrict__ a2, unsigned short* __restrict__ z, int n)
{
    __shared__ float xsT[F][XPAD];   // [k][nn]
    __shared__ float ps[NB][F];
    const int c = threadIdx.x;
    const int n0 = blockIdx.x * NB;

    #pragma unroll
    for (int nn = 0; nn < NB; ++nn) {
        int node = n0 + nn;
        xsT[c][nn] = (node < n) ? x[(long)node * F + c] : 0.f;
    }
    __syncthreads();

    float acc[NB];
    #pragma unroll
    for (int nn = 0; nn < NB; ++nn) acc[nn] = 0.f;

    #pragma unroll 4
    for (int k = 0; k < F; ++k) {
        float wv = w[k * F + c];
        float4 xa = *(const float4*)&xsT[k][0];
        float4 xb = *(const float4*)&xsT[k][4];
        acc[0] = fmaf(xa.x, wv, acc[0]);
        acc[1] = fmaf(xa.y, wv, acc[1]);
        acc[2] = fmaf(xa.z, wv, acc[2]);
        acc[3] = fmaf(xa.w, wv, acc[3]);
        acc[4] = fmaf(xb.x, wv, acc[4]);
        acc[5] = fmaf(xb.y, wv, acc[5]);
        acc[6] = fmaf(xb.z, wv, acc[6]);
        acc[7] = fmaf(xb.w, wv, acc[7]);
    }

    const int j = c & 7;
    const float a2v = a2[c];

    #pragma unroll
    for (int nn = 0; nn < NB; ++nn) ps[nn][c] = acc[nn] * a2v;
    __syncthreads();

    #pragma unroll
    for (int nn = 0; nn < NB; ++nn) {
        float t = 0.f;
        #pragma unroll
        for (int ii = 0; ii < 16; ++ii) t += ps[nn][ii * 8 + j];
        float s = t + sqrtf(t * t + 1.0f);
        int node = n0 + nn;
        if (node < n) {
            z[(long)node * FP + c] = f2bf(acc[nn] * s);
            if (c < NH) z[(long)node * FP + F + c] = f2bf(s);
        }
    }
}

__global__ __launch_bounds__(256)
void k_hist(const int* __restrict__ rows, int* __restrict__ cnt, int E)
{
    int e = blockIdx.x * blockDim.x + threadIdx.x;
    if (e < E) atomicAdd(&cnt[rows[e]], 1);
}

// ---- hierarchical exclusive scan over cnt[0..n) ----

__global__ __launch_bounds__(256)
void k_scan_partial(const int* __restrict__ cnt, int* __restrict__ blockSums, int n)
{
    const int t = threadIdx.x;
    const int base = blockIdx.x * SCAN_ELEMS + t * 4;
    int s = 0;
    #pragma unroll
    for (int k = 0; k < 4; ++k) {
        int i = base + k;
        if (i < n) s += cnt[i];
    }
    #pragma unroll
    for (int off = 32; off >= 1; off >>= 1) s += __shfl_down(s, off, 64);
    __shared__ int ws[4];
    if ((t & 63) == 0) ws[t >> 6] = s;
    __syncthreads();
    if (t == 0) blockSums[blockIdx.x] = ws[0] + ws[1] + ws[2] + ws[3];
}

__global__ __launch_bounds__(256)
void k_scan_mid(const int* __restrict__ blockSums, int* __restrict__ blockOff, int nblk)
{
    __shared__ int s[256];
    const int t = threadIdx.x;
    s[t] = (t < nblk) ? blockSums[t] : 0;
    __syncthreads();
    for (int off = 1; off < 256; off <<= 1) {
        int u = (t >= off) ? s[t - off] : 0;
        __syncthreads();
        s[t] += u;
        __syncthreads();
    }
    if (t < nblk) blockOff[t] = (t == 0) ? 0 : s[t - 1];
}

__global__ __launch_bounds__(256)
void k_scan_final(const int* __restrict__ cnt, const int* __restrict__ blockOff,
                  int* __restrict__ start, int* __restrict__ wr, int n)
{
    const int t = threadIdx.x;
    const int lane = t & 63;
    const int wv = t >> 6;
    const int base = blockIdx.x * SCAN_ELEMS + t * 4;

    int v[4];
    int sum4 = 0;
    #pragma unroll
    for (int k = 0; k < 4; ++k) {
        int i = base + k;
        v[k] = (i < n) ? cnt[i] : 0;
        sum4 += v[k];
    }

    int incl = sum4;
    #pragma unroll
    for (int off = 1; off < 64; off <<= 1) {
        int u = __shfl_up(incl, off, 64);
        if (lane >= off) incl += u;
    }

    __shared__ int waveSums[4];
    if (lane == 63) waveSums[wv] = incl;
    __syncthreads();
    if (t == 0) {
        int r = 0;
        #pragma unroll
        for (int w2 = 0; w2 < 4; ++w2) { int tmp = waveSums[w2]; waveSums[w2] = r; r += tmp; }
    }
    __syncthreads();

    int run = blockOff[blockIdx.x] + waveSums[wv] + (incl - sum4);
    #pragma unroll
    for (int k = 0; k < 4; ++k) {
        int i = base + k;
        if (i < n) { start[i] = run; wr[i] = run; }
        run += v[k];
    }
}

__global__ __launch_bounds__(256)
void k_scatter(const int* __restrict__ rows, const int* __restrict__ cols,
               const float* __restrict__ vals, int* __restrict__ wr,
               int2* __restrict__ ce, int E)
{
    int e = blockIdx.x * blockDim.x + threadIdx.x;
    if (e >= E) return;
    int r = rows[e];
    int pos = atomicAdd(&wr[r], 1);
    ce[pos] = make_int2(cols[e], __float_as_int(vals[e]));
}

// one wave per destination row; 4 edge-groups of 16 lanes; lane owns 8 bf16 cols
__global__ __launch_bounds__(256)
void k_spmm_pull(const int* __restrict__ start, const int* __restrict__ cnt,
                 const int2* __restrict__ ce, const unsigned short* __restrict__ z,
                 const float* __restrict__ bias, float* __restrict__ out, int n)
{
    const int wid  = (blockIdx.x * blockDim.x + threadIdx.x) >> 6;
    const int lane = threadIdx.x & 63;
    if (wid >= n) return;

    const int g   = lane >> 4;     // edge group 0..3
    const int c16 = lane & 15;     // 16B chunk within z row
    const int mq  = lane & 3;      // mask dword -> heads 2mq, 2mq+1

    const int s0  = start[wid];
    const int end = s0 + cnt[wid];

    float az[8];
    #pragma unroll
    for (int k = 0; k < 8; ++k) az[k] = 0.f;
    float am0 = 0.f, am1 = 0.f;

    for (int eb = s0; eb < end; eb += 4) {
        int e  = eb + g;
        bool ok = (e < end);
        int ec = ok ? e : (end - 1);          // end-1 >= s0 here since loop entered
        int2 p = ce[ec];
        float v = ok ? __int_as_float(p.y) : 0.f;
        const unsigned short* base = z + (long)p.x * FP;

        uint4 d = *(const uint4*)(base + 8 * c16);       // 8 cols
        unsigned int mdw = *((const unsigned int*)(base + F) + mq);

        az[0] = fmaf(v, bf_lo(d.x), az[0]);
        az[1] = fmaf(v, bf_hi(d.x), az[1]);
        az[2] = fmaf(v, bf_lo(d.y), az[2]);
        az[3] = fmaf(v, bf_hi(d.y), az[3]);
        az[4] = fmaf(v, bf_lo(d.z), az[4]);
        az[5] = fmaf(v, bf_hi(d.z), az[5]);
        az[6] = fmaf(v, bf_lo(d.w), az[6]);
        az[7] = fmaf(v, bf_hi(d.w), az[7]);
        am0   = fmaf(v, bf_lo(mdw), am0);
        am1   = fmaf(v, bf_hi(mdw), am1);
    }

    // reduce across the 4 edge groups (lanes l, l^16, l^32 hold same cols)
    #pragma unroll
    for (int k = 0; k < 8; ++k) {
        az[k] += __shfl_xor(az[k], 16, 64);
        az[k] += __shfl_xor(az[k], 32, 64);
    }
    am0 += __shfl_xor(am0, 16, 64); am0 += __shfl_xor(am0, 32, 64);
    am1 += __shfl_xor(am1, 16, 64); am1 += __shfl_xor(am1, 32, 64);

    // gather denominators for heads 0..7 from quartet lanes
    const int sq = lane & 60;
    float den[8];
    den[0] = __shfl(am0, sq | 0, 64);
    den[1] = __shfl(am1, sq | 0, 64);
    den[2] = __shfl(am0, sq | 1, 64);
    den[3] = __shfl(am1, sq | 1, 64);
    den[4] = __shfl(am0, sq | 2, 64);
    den[5] = __shfl(am1, sq | 2, 64);
    den[6] = __shfl(am0, sq | 3, 64);
    den[7] = __shfl(am1, sq | 3, 64);

    if (g == 0) {
        const float* bp = bias + 8 * c16;
        float4 b0 = *(const float4*)(bp);
        float4 b1 = *(const float4*)(bp + 4);
        float4 o0, o1;
        o0.x = az[0] / (den[0] + 1e-9f) + b0.x;
        o0.y = az[1] / (den[1] + 1e-9f) + b0.y;
        o0.z = az[2] / (den[2] + 1e-9f) + b0.z;
        o0.w = az[3] / (den[3] + 1e-9f) + b0.w;
        o1.x = az[4] / (den[4] + 1e-9f) + b1.x;
        o1.y = az[5] / (den[5] + 1e-9f) + b1.y;
        o1.z = az[6] / (den[6] + 1e-9f) + b1.z;
        o1.w = az[7] / (den[7] + 1e-9f) + b1.w;
        float* op = out + (long)wid * F + 8 * c16;
        *(float4*)(op)     = o0;
        *(float4*)(op + 4) = o1;
    }
}

extern "C" void kernel_launch(void* const* d_in, const int* in_sizes, int n_in,
                              void* d_out, int out_size, void* d_ws, size_t ws_size,
                              hipStream_t stream)
{
    const float* x    = (const float*)d_in[0];
    const int*   ei   = (const int*)d_in[1];
    const float* vals = (const float*)d_in[2];
    const float* w    = (const float*)d_in[3];
    const float* bias = (const float*)d_in[4];
    const float* a2   = (const float*)d_in[5];
    float* out = (float*)d_out;

    const int N = in_sizes[0] / F;
    const int E = in_sizes[2];
    const int* rows = ei;
    const int* cols = ei + E;

    const int nblk = (N + SCAN_ELEMS - 1) / SCAN_ELEMS;

    char* p = (char*)d_ws;
    unsigned short* z = (unsigned short*)p;  p += (((size_t)N * FP * sizeof(unsigned short) + 255) & ~255ull);
    int*   cnt      = (int*)p;    p += ((size_t)N + 64) * sizeof(int);
    int*   start    = (int*)p;    p += ((size_t)N + 64) * sizeof(int);
    int*   wr       = (int*)p;    p += ((size_t)N + 64) * sizeof(int);
    int*   blockSums= (int*)p;    p += 512 * sizeof(int);
    int*   blockOff = (int*)p;    p += 512 * sizeof(int);
    int2*  ce       = (int2*)p;

    hipMemsetAsync(cnt, 0, (size_t)N * sizeof(int), stream);

    dim3 b1(128), g1((N + NB - 1) / NB);
    k_gemm_attn<<<g1, b1, 0, stream>>>(x, w, a2, z, N);

    k_hist<<<dim3((E + 255) / 256), dim3(256), 0, stream>>>(rows, cnt, E);

    k_scan_partial<<<dim3(nblk), dim3(256), 0, stream>>>(cnt, blockSums, N);
    k_scan_mid<<<dim3(1), dim3(256), 0, stream>>>(blockSums, blockOff, nblk);
    k_scan_final<<<dim3(nblk), dim3(256), 0, stream>>>(cnt, blockOff, start, wr, N);

    k_scatter<<<dim3((E + 255) / 256), dim3(256), 0, stream>>>(rows, cols, vals, wr, ce, E);

    dim3 b5(256), g5((N + 3) / 4);
    k_spmm_pull<<<g5, b5, 0, stream>>>(start, cnt, ce, z, bias, out, N);
}

// Round 6
// 125.266 us; speedup vs baseline: 8.3508x; 1.1267x over previous
//
#include <hip/hip_runtime.h>
#include <hip/hip_bf16.h>

// SGAT layer, pull-based, bf16 z, MFMA split-bf16 GEMM:
//   z = [ (x@W) * s ; s ]  with s = attn2 + sqrt(attn2^2+1)   (N x 136, bf16)
//   x@W via 3-term split-bf16 MFMA: x_hi*W_hi + x_hi*W_lo + x_lo*W_hi (~fp32 accuracy)
//   CSR-group edges by destination row on device (hist + hierarchical scan + scatter)
//   per-row gather (4 edges in flight per wave): row_acc = sum_e vals[e] * z[cols[e]]
//   out = row_acc[:128] / (row_acc[128+head] + 1e-9) + bias (fused epilogue)

#define F 128      // F_OUT * H
#define FP 136     // F_OUT*H + H
#define NH 8
#define SCAN_ELEMS 1024
#define XS 264     // LDS x-tile row stride in bf16 elems (528 B, 16B-aligned, bank-clean)

typedef __attribute__((ext_vector_type(8))) short bf16x8;
typedef __attribute__((ext_vector_type(4))) float f32x4;

static __device__ __forceinline__ unsigned short f2bf(float f) {
    __hip_bfloat16 h = __float2bfloat16(f);   // RNE
    return *(unsigned short*)&h;
}
static __device__ __forceinline__ float bf2f(unsigned short u) {
    return __uint_as_float((unsigned int)u << 16);
}
static __device__ __forceinline__ float bf_lo(unsigned int u) { return __uint_as_float(u << 16); }
static __device__ __forceinline__ float bf_hi(unsigned int u) { return __uint_as_float(u & 0xFFFF0000u); }

// W(128x128 fp32, row-major [k][c]) -> Wt[col][0:128]=bf16 hi, Wt[col][128:256]=bf16 residual
__global__ __launch_bounds__(256)
void k_prep_w(const float* __restrict__ w, unsigned short* __restrict__ wt)
{
    int idx = blockIdx.x * 256 + threadIdx.x;   // 16384 total
    int col = idx >> 7;
    int k   = idx & 127;
    float v = w[k * F + col];
    unsigned short h = f2bf(v);
    unsigned short lo = f2bf(v - bf2f(h));
    wt[col * 256 + k]       = h;
    wt[col * 256 + 128 + k] = lo;
}

// 64 nodes x 128 cols per 256-thread block; wave w owns cols [w*32, w*32+32)
__global__ __launch_bounds__(256)
void k_gemm_attn(const float* __restrict__ x, const unsigned short* __restrict__ wt,
                 const float* __restrict__ a2, unsigned short* __restrict__ z, int n)
{
    __shared__ __align__(16) unsigned short xls[64 * XS];   // [node][k: 0..127 hi | 128..255 lo]
    __shared__ float part[4 * 64 * 8];                      // [wave][node][head]
    __shared__ float sarr[64 * 8];                          // [node][head]

    const int t  = threadIdx.x;
    const int l  = t & 63;
    const int w  = t >> 6;         // wave 0..3
    const int lm = l & 15;
    const int lq = l >> 4;         // 0..3
    const int n0 = blockIdx.x * 64;

    // ---- stage x tile as bf16 hi/lo (coalesced float4 loads, bank-clean b64 writes) ----
    #pragma unroll
    for (int i = 0; i < 8; ++i) {
        int idx  = i * 256 + t;
        int node = idx >> 5;           // 32 float4 per node
        int k0   = (idx & 31) * 4;
        int gn   = n0 + node;
        float4 v = (gn < n) ? *(const float4*)(x + (long)gn * F + k0)
                            : make_float4(0.f, 0.f, 0.f, 0.f);
        ushort4 h, lo;
        h.x  = f2bf(v.x); h.y  = f2bf(v.y); h.z  = f2bf(v.z); h.w  = f2bf(v.w);
        lo.x = f2bf(v.x - bf2f(h.x));
        lo.y = f2bf(v.y - bf2f(h.y));
        lo.z = f2bf(v.z - bf2f(h.z));
        lo.w = f2bf(v.w - bf2f(h.w));
        *(ushort4*)(&xls[node * XS + k0])       = h;
        *(ushort4*)(&xls[node * XS + 128 + k0]) = lo;
    }
    __syncthreads();

    // ---- MFMA main loop: acc[rf][cf] covers rows rf*16+.., cols wc+cf*16+.. ----
    const int wc = w * 32;
    f32x4 acc[4][2];
    #pragma unroll
    for (int rf = 0; rf < 4; ++rf)
        #pragma unroll
        for (int cf = 0; cf < 2; ++cf)
            acc[rf][cf] = (f32x4){0.f, 0.f, 0.f, 0.f};

    #pragma unroll
    for (int ks = 0; ks < 4; ++ks) {
        const int koff = ks * 32 + lq * 8;
        bf16x8 bh[2], bl[2];
        #pragma unroll
        for (int cf = 0; cf < 2; ++cf) {
            const unsigned short* bp = wt + (wc + cf * 16 + lm) * 256 + koff;
            bh[cf] = *(const bf16x8*)(bp);          // W_hi fragment (L2-hot)
            bl[cf] = *(const bf16x8*)(bp + 128);    // W_lo fragment
        }
        bf16x8 ah[4], al[4];
        #pragma unroll
        for (int rf = 0; rf < 4; ++rf) {
            const unsigned short* ap = &xls[(rf * 16 + lm) * XS + koff];
            ah[rf] = *(const bf16x8*)(ap);
            al[rf] = *(const bf16x8*)(ap + 128);
        }
        #pragma unroll
        for (int rf = 0; rf < 4; ++rf)
            #pragma unroll
            for (int cf = 0; cf < 2; ++cf) {
                acc[rf][cf] = __builtin_amdgcn_mfma_f32_16x16x32_bf16(ah[rf], bh[cf], acc[rf][cf], 0, 0, 0);
                acc[rf][cf] = __builtin_amdgcn_mfma_f32_16x16x32_bf16(ah[rf], bl[cf], acc[rf][cf], 0, 0, 0);
                acc[rf][cf] = __builtin_amdgcn_mfma_f32_16x16x32_bf16(al[rf], bh[cf], acc[rf][cf], 0, 0, 0);
            }
    }

    // ---- attn2 partials: per-lane over own cols, shfl_xor(8) pairs same-head cols ----
    const float a20 = a2[wc + lm];
    const float a21 = a2[wc + 16 + lm];
    const int j = l & 7;

    #pragma unroll
    for (int rf = 0; rf < 4; ++rf) {
        #pragma unroll
        for (int r = 0; r < 4; ++r) {
            float pl = acc[rf][0][r] * a20 + acc[rf][1][r] * a21;
            pl += __shfl_xor(pl, 8, 64);
            if ((l & 8) == 0) {
                int node = rf * 16 + lq * 4 + r;
                part[(w * 64 + node) * 8 + j] = pl;
            }
        }
    }
    __syncthreads();

    // ---- s = attn2 + sqrt(attn2^2+1); write z mask col ----
    #pragma unroll
    for (int eo = 0; eo < 2; ++eo) {
        int e    = eo * 256 + t;       // 0..511 = 64 nodes x 8 heads
        int node = e >> 3;
        int jj   = e & 7;
        float ts = part[(0 * 64 + node) * 8 + jj] + part[(1 * 64 + node) * 8 + jj]
                 + part[(2 * 64 + node) * 8 + jj] + part[(3 * 64 + node) * 8 + jj];
        float s = ts + sqrtf(ts * ts + 1.0f);
        sarr[node * 8 + jj] = s;
        int gn = n0 + node;
        if (gn < n) z[(long)gn * FP + F + jj] = f2bf(s);
    }
    __syncthreads();

    // ---- scale by s[head] and write z (bf16) ----
    #pragma unroll
    for (int rf = 0; rf < 4; ++rf) {
        #pragma unroll
        for (int r = 0; r < 4; ++r) {
            int node = rf * 16 + lq * 4 + r;
            int gn = n0 + node;
            if (gn < n) {
                float sv = sarr[node * 8 + j];
                #pragma unroll
                for (int cf = 0; cf < 2; ++cf) {
                    int c = wc + cf * 16 + lm;
                    z[(long)gn * FP + c] = f2bf(acc[rf][cf][r] * sv);
                }
            }
        }
    }
}

__global__ __launch_bounds__(256)
void k_hist(const int* __restrict__ rows, int* __restrict__ cnt, int E)
{
    int e = blockIdx.x * blockDim.x + threadIdx.x;
    if (e < E) atomicAdd(&cnt[rows[e]], 1);
}

// ---- hierarchical exclusive scan over cnt[0..n) ----

__global__ __launch_bounds__(256)
void k_scan_partial(const int* __restrict__ cnt, int* __restrict__ blockSums, int n)
{
    const int t = threadIdx.x;
    const int base = blockIdx.x * SCAN_ELEMS + t * 4;
    int s = 0;
    #pragma unroll
    for (int k = 0; k < 4; ++k) {
        int i = base + k;
        if (i < n) s += cnt[i];
    }
    #pragma unroll
    for (int off = 32; off >= 1; off >>= 1) s += __shfl_down(s, off, 64);
    __shared__ int ws[4];
    if ((t & 63) == 0) ws[t >> 6] = s;
    __syncthreads();
    if (t == 0) blockSums[blockIdx.x] = ws[0] + ws[1] + ws[2] + ws[3];
}

__global__ __launch_bounds__(256)
void k_scan_mid(const int* __restrict__ blockSums, int* __restrict__ blockOff, int nblk)
{
    __shared__ int s[256];
    const int t = threadIdx.x;
    s[t] = (t < nblk) ? blockSums[t] : 0;
    __syncthreads();
    for (int off = 1; off < 256; off <<= 1) {
        int u = (t >= off) ? s[t - off] : 0;
        __syncthreads();
        s[t] += u;
        __syncthreads();
    }
    if (t < nblk) blockOff[t] = (t == 0) ? 0 : s[t - 1];
}

__global__ __launch_bounds__(256)
void k_scan_final(const int* __restrict__ cnt, const int* __restrict__ blockOff,
                  int* __restrict__ start, int* __restrict__ wr, int n)
{
    const int t = threadIdx.x;
    const int lane = t & 63;
    const int wv = t >> 6;
    const int base = blockIdx.x * SCAN_ELEMS + t * 4;

    int v[4];
    int sum4 = 0;
    #pragma unroll
    for (int k = 0; k < 4; ++k) {
        int i = base + k;
        v[k] = (i < n) ? cnt[i] : 0;
        sum4 += v[k];
    }

    int incl = sum4;
    #pragma unroll
    for (int off = 1; off < 64; off <<= 1) {
        int u = __shfl_up(incl, off, 64);
        if (lane >= off) incl += u;
    }

    __shared__ int waveSums[4];
    if (lane == 63) waveSums[wv] = incl;
    __syncthreads();
    if (t == 0) {
        int r = 0;
        #pragma unroll
        for (int w2 = 0; w2 < 4; ++w2) { int tmp = waveSums[w2]; waveSums[w2] = r; r += tmp; }
    }
    __syncthreads();

    int run = blockOff[blockIdx.x] + waveSums[wv] + (incl - sum4);
    #pragma unroll
    for (int k = 0; k < 4; ++k) {
        int i = base + k;
        if (i < n) { start[i] = run; wr[i] = run; }
        run += v[k];
    }
}

__global__ __launch_bounds__(256)
void k_scatter(const int* __restrict__ rows, const int* __restrict__ cols,
               const float* __restrict__ vals, int* __restrict__ wr,
               int2* __restrict__ ce, int E)
{
    int e = blockIdx.x * blockDim.x + threadIdx.x;
    if (e >= E) return;
    int r = rows[e];
    int pos = atomicAdd(&wr[r], 1);
    ce[pos] = make_int2(cols[e], __float_as_int(vals[e]));
}

// one wave per destination row; 4 edge-groups of 16 lanes; lane owns 8 bf16 cols
__global__ __launch_bounds__(256)
void k_spmm_pull(const int* __restrict__ start, const int* __restrict__ cnt,
                 const int2* __restrict__ ce, const unsigned short* __restrict__ z,
                 const float* __restrict__ bias, float* __restrict__ out, int n)
{
    const int wid  = (blockIdx.x * blockDim.x + threadIdx.x) >> 6;
    const int lane = threadIdx.x & 63;
    if (wid >= n) return;

    const int g   = lane >> 4;     // edge group 0..3
    const int c16 = lane & 15;     // 16B chunk within z row
    const int mq  = lane & 3;      // mask dword -> heads 2mq, 2mq+1

    const int s0  = start[wid];
    const int end = s0 + cnt[wid];

    float az[8];
    #pragma unroll
    for (int k = 0; k < 8; ++k) az[k] = 0.f;
    float am0 = 0.f, am1 = 0.f;

    for (int eb = s0; eb < end; eb += 4) {
        int e  = eb + g;
        bool ok = (e < end);
        int ec = ok ? e : (end - 1);
        int2 p = ce[ec];
        float v = ok ? __int_as_float(p.y) : 0.f;
        const unsigned short* base = z + (long)p.x * FP;

        uint4 d = *(const uint4*)(base + 8 * c16);
        unsigned int mdw = *((const unsigned int*)(base + F) + mq);

        az[0] = fmaf(v, bf_lo(d.x), az[0]);
        az[1] = fmaf(v, bf_hi(d.x), az[1]);
        az[2] = fmaf(v, bf_lo(d.y), az[2]);
        az[3] = fmaf(v, bf_hi(d.y), az[3]);
        az[4] = fmaf(v, bf_lo(d.z), az[4]);
        az[5] = fmaf(v, bf_hi(d.z), az[5]);
        az[6] = fmaf(v, bf_lo(d.w), az[6]);
        az[7] = fmaf(v, bf_hi(d.w), az[7]);
        am0   = fmaf(v, bf_lo(mdw), am0);
        am1   = fmaf(v, bf_hi(mdw), am1);
    }

    #pragma unroll
    for (int k = 0; k < 8; ++k) {
        az[k] += __shfl_xor(az[k], 16, 64);
        az[k] += __shfl_xor(az[k], 32, 64);
    }
    am0 += __shfl_xor(am0, 16, 64); am0 += __shfl_xor(am0, 32, 64);
    am1 += __shfl_xor(am1, 16, 64); am1 += __shfl_xor(am1, 32, 64);

    const int sq = lane & 60;
    float den[8];
    den[0] = __shfl(am0, sq | 0, 64);
    den[1] = __shfl(am1, sq | 0, 64);
    den[2] = __shfl(am0, sq | 1, 64);
    den[3] = __shfl(am1, sq | 1, 64);
    den[4] = __shfl(am0, sq | 2, 64);
    den[5] = __shfl(am1, sq | 2, 64);
    den[6] = __shfl(am0, sq | 3, 64);
    den[7] = __shfl(am1, sq | 3, 64);

    if (g == 0) {
        const float* bp = bias + 8 * c16;
        float4 b0 = *(const float4*)(bp);
        float4 b1 = *(const float4*)(bp + 4);
        float4 o0, o1;
        o0.x = az[0] / (den[0] + 1e-9f) + b0.x;
        o0.y = az[1] / (den[1] + 1e-9f) + b0.y;
        o0.z = az[2] / (den[2] + 1e-9f) + b0.z;
        o0.w = az[3] / (den[3] + 1e-9f) + b0.w;
        o1.x = az[4] / (den[4] + 1e-9f) + b1.x;
        o1.y = az[5] / (den[5] + 1e-9f) + b1.y;
        o1.z = az[6] / (den[6] + 1e-9f) + b1.z;
        o1.w = az[7] / (den[7] + 1e-9f) + b1.w;
        float* op = out + (long)wid * F + 8 * c16;
        *(float4*)(op)     = o0;
        *(float4*)(op + 4) = o1;
    }
}

extern "C" void kernel_launch(void* const* d_in, const int* in_sizes, int n_in,
                              void* d_out, int out_size, void* d_ws, size_t ws_size,
                              hipStream_t stream)
{
    const float* x    = (const float*)d_in[0];
    const int*   ei   = (const int*)d_in[1];
    const float* vals = (const float*)d_in[2];
    const float* w    = (const float*)d_in[3];
    const float* bias = (const float*)d_in[4];
    const float* a2   = (const float*)d_in[5];
    float* out = (float*)d_out;

    const int N = in_sizes[0] / F;
    const int E = in_sizes[2];
    const int* rows = ei;
    const int* cols = ei + E;

    const int nblk = (N + SCAN_ELEMS - 1) / SCAN_ELEMS;

    char* p = (char*)d_ws;
    unsigned short* z  = (unsigned short*)p;  p += (((size_t)N * FP * sizeof(unsigned short) + 255) & ~255ull);
    unsigned short* wt = (unsigned short*)p;  p += 128 * 256 * sizeof(unsigned short);   // 64 KB
    int*   cnt      = (int*)p;    p += ((size_t)N + 64) * sizeof(int);
    int*   start    = (int*)p;    p += ((size_t)N + 64) * sizeof(int);
    int*   wr       = (int*)p;    p += ((size_t)N + 64) * sizeof(int);
    int*   blockSums= (int*)p;    p += 512 * sizeof(int);
    int*   blockOff = (int*)p;    p += 512 * sizeof(int);
    int2*  ce       = (int2*)p;

    hipMemsetAsync(cnt, 0, (size_t)N * sizeof(int), stream);

    k_prep_w<<<dim3(64), dim3(256), 0, stream>>>(w, wt);

    dim3 b1(256), g1((N + 63) / 64);
    k_gemm_attn<<<g1, b1, 0, stream>>>(x, wt, a2, z, N);

    k_hist<<<dim3((E + 255) / 256), dim3(256), 0, stream>>>(rows, cnt, E);

    k_scan_partial<<<dim3(nblk), dim3(256), 0, stream>>>(cnt, blockSums, N);
    k_scan_mid<<<dim3(1), dim3(256), 0, stream>>>(blockSums, blockOff, nblk);
    k_scan_final<<<dim3(nblk), dim3(256), 0, stream>>>(cnt, blockOff, start, wr, N);

    k_scatter<<<dim3((E + 255) / 256), dim3(256), 0, stream>>>(rows, cols, vals, wr, ce, E);

    dim3 b5(256), g5((N + 3) / 4);
    k_spmm_pull<<<g5, b5, 0, stream>>>(start, cnt, ce, z, bias, out, N);
}

// Round 7
// 117.937 us; speedup vs baseline: 8.8697x; 1.0621x over previous
//
#include <hip/hip_runtime.h>
#include <hip/hip_bf16.h>

// SGAT layer, pull-based, bf16 z, MFMA split-bf16 GEMM, LDS-staged coalesced z writes.
//   z = [ (x@W) * s ; s ]  with s = attn2 + sqrt(attn2^2+1)   (N x 136, bf16)
//   x@W via 3-term split-bf16 MFMA: x_hi*W_hi + x_hi*W_lo + x_lo*W_hi (~fp32 accuracy)
//   CSR-group edges by destination row (hist + 2-pass scan + scatter), then
//   per-row gather (4 edges in flight per wave) with fused normalize/bias epilogue.

#define F 128      // F_OUT * H
#define FP 136     // F_OUT*H + H
#define NH 8
#define SCAN_ELEMS 1024
#define XS 264     // x staging row stride (ushorts): hi|lo, 16B-aligned
#define ZS 144     // z staging row stride (ushorts): 288B, 16B-aligned, bank-spread

typedef __attribute__((ext_vector_type(8))) short bf16x8;
typedef __attribute__((ext_vector_type(4))) float f32x4;

static __device__ __forceinline__ unsigned short f2bf(float f) {
    __hip_bfloat16 h = __float2bfloat16(f);   // RNE
    return *(unsigned short*)&h;
}
static __device__ __forceinline__ float bf2f(unsigned short u) {
    return __uint_as_float((unsigned int)u << 16);
}
static __device__ __forceinline__ float bf_lo(unsigned int u) { return __uint_as_float(u << 16); }
static __device__ __forceinline__ float bf_hi(unsigned int u) { return __uint_as_float(u & 0xFFFF0000u); }

// W(128x128 fp32 [k][c]) -> Wt[col][0:128]=bf16 hi, [128:256]=bf16 residual; also zero cnt
__global__ __launch_bounds__(256)
void k_prep_w(const float* __restrict__ w, unsigned short* __restrict__ wt,
              int* __restrict__ cnt, int ncnt)
{
    int idx = blockIdx.x * 256 + threadIdx.x;   // 16384 total
    int col = idx >> 7;
    int k   = idx & 127;
    float v = w[k * F + col];
    unsigned short h = f2bf(v);
    unsigned short lo = f2bf(v - bf2f(h));
    wt[col * 256 + k]       = h;
    wt[col * 256 + 128 + k] = lo;
    for (int i = idx; i < ncnt; i += 64 * 256) cnt[i] = 0;
}

// 64 nodes x 128 cols per 256-thread block; wave w owns cols [w*32, w*32+32)
__global__ __launch_bounds__(256)
void k_gemm_attn(const float* __restrict__ x, const unsigned short* __restrict__ wt,
                 const float* __restrict__ a2, unsigned short* __restrict__ z, int n)
{
    __shared__ __align__(16) unsigned short xls[64 * XS];   // reused as zls[64*ZS] later
    __shared__ float part[4 * 64 * 8];                      // [wave][node][head]
    __shared__ float sarr[64 * 8];                          // [node][head]

    const int t  = threadIdx.x;
    const int l  = t & 63;
    const int w  = t >> 6;
    const int lm = l & 15;
    const int lq = l >> 4;
    const int n0 = blockIdx.x * 64;

    // ---- stage x tile as bf16 hi/lo ----
    #pragma unroll
    for (int i = 0; i < 8; ++i) {
        int idx  = i * 256 + t;
        int node = idx >> 5;
        int k0   = (idx & 31) * 4;
        int gn   = n0 + node;
        float4 v = (gn < n) ? *(const float4*)(x + (long)gn * F + k0)
                            : make_float4(0.f, 0.f, 0.f, 0.f);
        ushort4 h, lo;
        h.x  = f2bf(v.x); h.y  = f2bf(v.y); h.z  = f2bf(v.z); h.w  = f2bf(v.w);
        lo.x = f2bf(v.x - bf2f(h.x));
        lo.y = f2bf(v.y - bf2f(h.y));
        lo.z = f2bf(v.z - bf2f(h.z));
        lo.w = f2bf(v.w - bf2f(h.w));
        *(ushort4*)(&xls[node * XS + k0])       = h;
        *(ushort4*)(&xls[node * XS + 128 + k0]) = lo;
    }
    __syncthreads();

    // ---- MFMA main loop ----
    const int wc = w * 32;
    f32x4 acc[4][2];
    #pragma unroll
    for (int rf = 0; rf < 4; ++rf)
        #pragma unroll
        for (int cf = 0; cf < 2; ++cf)
            acc[rf][cf] = (f32x4){0.f, 0.f, 0.f, 0.f};

    #pragma unroll
    for (int ks = 0; ks < 4; ++ks) {
        const int koff = ks * 32 + lq * 8;
        bf16x8 bh[2], bl[2];
        #pragma unroll
        for (int cf = 0; cf < 2; ++cf) {
            const unsigned short* bp = wt + (wc + cf * 16 + lm) * 256 + koff;
            bh[cf] = *(const bf16x8*)(bp);
            bl[cf] = *(const bf16x8*)(bp + 128);
        }
        bf16x8 ah[4], al[4];
        #pragma unroll
        for (int rf = 0; rf < 4; ++rf) {
            const unsigned short* ap = &xls[(rf * 16 + lm) * XS + koff];
            ah[rf] = *(const bf16x8*)(ap);
            al[rf] = *(const bf16x8*)(ap + 128);
        }
        #pragma unroll
        for (int rf = 0; rf < 4; ++rf)
            #pragma unroll
            for (int cf = 0; cf < 2; ++cf) {
                acc[rf][cf] = __builtin_amdgcn_mfma_f32_16x16x32_bf16(ah[rf], bh[cf], acc[rf][cf], 0, 0, 0);
                acc[rf][cf] = __builtin_amdgcn_mfma_f32_16x16x32_bf16(ah[rf], bl[cf], acc[rf][cf], 0, 0, 0);
                acc[rf][cf] = __builtin_amdgcn_mfma_f32_16x16x32_bf16(al[rf], bh[cf], acc[rf][cf], 0, 0, 0);
            }
    }

    // ---- attn2 partials ----
    const float a20 = a2[wc + lm];
    const float a21 = a2[wc + 16 + lm];
    const int j = l & 7;

    #pragma unroll
    for (int rf = 0; rf < 4; ++rf) {
        #pragma unroll
        for (int r = 0; r < 4; ++r) {
            float pl = acc[rf][0][r] * a20 + acc[rf][1][r] * a21;
            pl += __shfl_xor(pl, 8, 64);
            if ((l & 8) == 0) {
                int node = rf * 16 + lq * 4 + r;
                part[(w * 64 + node) * 8 + j] = pl;
            }
        }
    }
    __syncthreads();   // after this, xls no longer read -> safe to reuse as zls

    unsigned short* zls = xls;

    // ---- s = attn2 + sqrt(attn2^2+1); mask cols into LDS z tile ----
    #pragma unroll
    for (int eo = 0; eo < 2; ++eo) {
        int e    = eo * 256 + t;       // 64 nodes x 8 heads
        int node = e >> 3;
        int jj   = e & 7;
        float ts = part[(0 * 64 + node) * 8 + jj] + part[(1 * 64 + node) * 8 + jj]
                 + part[(2 * 64 + node) * 8 + jj] + part[(3 * 64 + node) * 8 + jj];
        float s = ts + sqrtf(ts * ts + 1.0f);
        sarr[node * 8 + jj] = s;
        zls[node * ZS + F + jj] = f2bf(s);
    }
    __syncthreads();

    // ---- scale by s[head] into LDS z tile ----
    #pragma unroll
    for (int rf = 0; rf < 4; ++rf) {
        #pragma unroll
        for (int r = 0; r < 4; ++r) {
            int node = rf * 16 + lq * 4 + r;
            float sv = sarr[node * 8 + j];
            #pragma unroll
            for (int cf = 0; cf < 2; ++cf) {
                int c = wc + cf * 16 + lm;
                zls[node * ZS + c] = f2bf(acc[rf][cf][r] * sv);
            }
        }
    }
    __syncthreads();

    // ---- coalesced z write: 64 rows x 17 dwordx4 (z rows are 16B-aligned: 272B) ----
    #pragma unroll
    for (int i = 0; i < 5; ++i) {
        int idx = i * 256 + t;
        if (idx < 64 * 17) {
            int row = idx / 17;
            int q   = idx - row * 17;
            int gn  = n0 + row;
            if (gn < n) {
                uint4 v = *(const uint4*)(&zls[row * ZS + q * 8]);
                ((uint4*)(z + (long)gn * FP))[q] = v;
            }
        }
    }
}

__global__ __launch_bounds__(256)
void k_hist(const int* __restrict__ rows, int* __restrict__ cnt, int E)
{
    int e = blockIdx.x * blockDim.x + threadIdx.x;
    if (e < E) atomicAdd(&cnt[rows[e]], 1);
}

// pass 1: per-1024-elem block reduce -> blockSums
__global__ __launch_bounds__(256)
void k_scan_partial(const int* __restrict__ cnt, int* __restrict__ blockSums, int n)
{
    const int t = threadIdx.x;
    const int base = blockIdx.x * SCAN_ELEMS + t * 4;
    int s = 0;
    #pragma unroll
    for (int k = 0; k < 4; ++k) {
        int i = base + k;
        if (i < n) s += cnt[i];
    }
    #pragma unroll
    for (int off = 32; off >= 1; off >>= 1) s += __shfl_down(s, off, 64);
    __shared__ int ws[4];
    if ((t & 63) == 0) ws[t >> 6] = s;
    __syncthreads();
    if (t == 0) blockSums[blockIdx.x] = ws[0] + ws[1] + ws[2] + ws[3];
}

// pass 2 (mid merged): block offset computed in-kernel from blockSums (nblk <= 64)
__global__ __launch_bounds__(256)
void k_scan_final(const int* __restrict__ cnt, const int* __restrict__ blockSums,
                  int* __restrict__ start, int* __restrict__ wr, int n, int nblk, int E)
{
    __shared__ int boffs;
    const int t = threadIdx.x;
    const int lane = t & 63;
    const int wv = t >> 6;

    if (t < 64) {
        int v = (t < nblk && t < blockIdx.x) ? blockSums[t] : 0;
        #pragma unroll
        for (int off = 32; off >= 1; off >>= 1) v += __shfl_down(v, off, 64);
        if (t == 0) boffs = v;
    }

    const int base = blockIdx.x * SCAN_ELEMS + t * 4;
    int v[4];
    int sum4 = 0;
    #pragma unroll
    for (int k = 0; k < 4; ++k) {
        int i = base + k;
        v[k] = (i < n) ? cnt[i] : 0;
        sum4 += v[k];
    }

    int incl = sum4;
    #pragma unroll
    for (int off = 1; off < 64; off <<= 1) {
        int u = __shfl_up(incl, off, 64);
        if (lane >= off) incl += u;
    }

    __shared__ int waveSums[4];
    if (lane == 63) waveSums[wv] = incl;
    __syncthreads();
    if (t == 0) {
        int r = 0;
        #pragma unroll
        for (int w2 = 0; w2 < 4; ++w2) { int tmp = waveSums[w2]; waveSums[w2] = r; r += tmp; }
    }
    __syncthreads();

    int run = boffs + waveSums[wv] + (incl - sum4);
    #pragma unroll
    for (int k = 0; k < 4; ++k) {
        int i = base + k;
        if (i < n) { start[i] = run; wr[i] = run; }
        run += v[k];
        if (i == n - 1) start[n] = E;   // CSR end pointer
    }
}

__global__ __launch_bounds__(256)
void k_scatter(const int* __restrict__ rows, const int* __restrict__ cols,
               const float* __restrict__ vals, int* __restrict__ wr,
               int2* __restrict__ ce, int E)
{
    int e = blockIdx.x * blockDim.x + threadIdx.x;
    if (e >= E) return;
    int r = rows[e];
    int pos = atomicAdd(&wr[r], 1);
    ce[pos] = make_int2(cols[e], __float_as_int(vals[e]));
}

// one wave per destination row; 4 edge-groups of 16 lanes; lane owns 8 bf16 cols
__global__ __launch_bounds__(256)
void k_spmm_pull(const int* __restrict__ start, const int2* __restrict__ ce,
                 const unsigned short* __restrict__ z, const float* __restrict__ bias,
                 float* __restrict__ out, int n)
{
    const int wid  = (blockIdx.x * blockDim.x + threadIdx.x) >> 6;
    const int lane = threadIdx.x & 63;
    if (wid >= n) return;

    const int g   = lane >> 4;
    const int c16 = lane & 15;
    const int mq  = lane & 3;

    const int s0  = start[wid];
    const int end = start[wid + 1];

    float az[8];
    #pragma unroll
    for (int k = 0; k < 8; ++k) az[k] = 0.f;
    float am0 = 0.f, am1 = 0.f;

    for (int eb = s0; eb < end; eb += 4) {
        int e  = eb + g;
        bool ok = (e < end);
        int ec = ok ? e : (end - 1);
        int2 p = ce[ec];
        float v = ok ? __int_as_float(p.y) : 0.f;
        const unsigned short* base = z + (long)p.x * FP;

        uint4 d = *(const uint4*)(base + 8 * c16);
        unsigned int mdw = *((const unsigned int*)(base + F) + mq);

        az[0] = fmaf(v, bf_lo(d.x), az[0]);
        az[1] = fmaf(v, bf_hi(d.x), az[1]);
        az[2] = fmaf(v, bf_lo(d.y), az[2]);
        az[3] = fmaf(v, bf_hi(d.y), az[3]);
        az[4] = fmaf(v, bf_lo(d.z), az[4]);
        az[5] = fmaf(v, bf_hi(d.z), az[5]);
        az[6] = fmaf(v, bf_lo(d.w), az[6]);
        az[7] = fmaf(v, bf_hi(d.w), az[7]);
        am0   = fmaf(v, bf_lo(mdw), am0);
        am1   = fmaf(v, bf_hi(mdw), am1);
    }

    #pragma unroll
    for (int k = 0; k < 8; ++k) {
        az[k] += __shfl_xor(az[k], 16, 64);
        az[k] += __shfl_xor(az[k], 32, 64);
    }
    am0 += __shfl_xor(am0, 16, 64); am0 += __shfl_xor(am0, 32, 64);
    am1 += __shfl_xor(am1, 16, 64); am1 += __shfl_xor(am1, 32, 64);

    const int sq = lane & 60;
    float den[8];
    den[0] = __shfl(am0, sq | 0, 64);
    den[1] = __shfl(am1, sq | 0, 64);
    den[2] = __shfl(am0, sq | 1, 64);
    den[3] = __shfl(am1, sq | 1, 64);
    den[4] = __shfl(am0, sq | 2, 64);
    den[5] = __shfl(am1, sq | 2, 64);
    den[6] = __shfl(am0, sq | 3, 64);
    den[7] = __shfl(am1, sq | 3, 64);

    if (g == 0) {
        const float* bp = bias + 8 * c16;
        float4 b0 = *(const float4*)(bp);
        float4 b1 = *(const float4*)(bp + 4);
        float4 o0, o1;
        o0.x = az[0] / (den[0] + 1e-9f) + b0.x;
        o0.y = az[1] / (den[1] + 1e-9f) + b0.y;
        o0.z = az[2] / (den[2] + 1e-9f) + b0.z;
        o0.w = az[3] / (den[3] + 1e-9f) + b0.w;
        o1.x = az[4] / (den[4] + 1e-9f) + b1.x;
        o1.y = az[5] / (den[5] + 1e-9f) + b1.y;
        o1.z = az[6] / (den[6] + 1e-9f) + b1.z;
        o1.w = az[7] / (den[7] + 1e-9f) + b1.w;
        float* op = out + (long)wid * F + 8 * c16;
        *(float4*)(op)     = o0;
        *(float4*)(op + 4) = o1;
    }
}

extern "C" void kernel_launch(void* const* d_in, const int* in_sizes, int n_in,
                              void* d_out, int out_size, void* d_ws, size_t ws_size,
                              hipStream_t stream)
{
    const float* x    = (const float*)d_in[0];
    const int*   ei   = (const int*)d_in[1];
    const float* vals = (const float*)d_in[2];
    const float* w    = (const float*)d_in[3];
    const float* bias = (const float*)d_in[4];
    const float* a2   = (const float*)d_in[5];
    float* out = (float*)d_out;

    const int N = in_sizes[0] / F;
    const int E = in_sizes[2];
    const int* rows = ei;
    const int* cols = ei + E;

    const int nblk = (N + SCAN_ELEMS - 1) / SCAN_ELEMS;   // 49 (<=64 required)

    char* p = (char*)d_ws;
    unsigned short* z  = (unsigned short*)p;  p += (((size_t)N * FP * sizeof(unsigned short) + 255) & ~255ull);
    unsigned short* wt = (unsigned short*)p;  p += 128 * 256 * sizeof(unsigned short);
    int*   cnt      = (int*)p;    p += ((size_t)N + 64) * sizeof(int);
    int*   start    = (int*)p;    p += ((size_t)N + 64) * sizeof(int);
    int*   wr       = (int*)p;    p += ((size_t)N + 64) * sizeof(int);
    int*   blockSums= (int*)p;    p += 512 * sizeof(int);
    int2*  ce       = (int2*)p;

    k_prep_w<<<dim3(64), dim3(256), 0, stream>>>(w, wt, cnt, N);

    dim3 b1(256), g1((N + 63) / 64);
    k_gemm_attn<<<g1, b1, 0, stream>>>(x, wt, a2, z, N);

    k_hist<<<dim3((E + 255) / 256), dim3(256), 0, stream>>>(rows, cnt, E);

    k_scan_partial<<<dim3(nblk), dim3(256), 0, stream>>>(cnt, blockSums, N);
    k_scan_final<<<dim3(nblk), dim3(256), 0, stream>>>(cnt, blockSums, start, wr, N, nblk, E);

    k_scatter<<<dim3((E + 255) / 256), dim3(256), 0, stream>>>(rows, cols, vals, wr, ce, E);

    dim3 b5(256), g5((N + 3) / 4);
    k_spmm_pull<<<g5, b5, 0, stream>>>(start, ce, z, bias, out, N);
}

// Round 8
// 96.469 us; speedup vs baseline: 10.8435x; 1.2225x over previous
//
#include <hip/hip_runtime.h>
#include <hip/hip_bf16.h>

// SGAT layer, pull-based, bf16 z, MFMA split-bf16 GEMM, group-per-row SpMM.
//   z = [ (x@W) * s ; s ]  with s = attn2 + sqrt(attn2^2+1)   (N x 136, bf16)
//   x@W via 3-term split-bf16 MFMA: x_hi*W_hi + x_hi*W_lo + x_lo*W_hi (~fp32 accuracy)
//   CSR-group edges by destination row (hist+rank, scan, atomic-free scatter), then
//   16-lane-group-per-row gather with fused normalize/bias epilogue.

#define F 128      // F_OUT * H
#define FP 136     // F_OUT*H + H
#define NH 8
#define SCAN_ELEMS 1024
#define XS 264     // x staging row stride (ushorts): hi|lo, 16B-aligned
#define ZS 144     // z staging row stride (ushorts): 288B, 16B-aligned, bank-spread

typedef __attribute__((ext_vector_type(8))) short bf16x8;
typedef __attribute__((ext_vector_type(4))) float f32x4;

static __device__ __forceinline__ unsigned short f2bf(float f) {
    __hip_bfloat16 h = __float2bfloat16(f);   // RNE
    return *(unsigned short*)&h;
}
static __device__ __forceinline__ float bf2f(unsigned short u) {
    return __uint_as_float((unsigned int)u << 16);
}
static __device__ __forceinline__ float bf_lo(unsigned int u) { return __uint_as_float(u << 16); }
static __device__ __forceinline__ float bf_hi(unsigned int u) { return __uint_as_float(u & 0xFFFF0000u); }

// W(128x128 fp32 [k][c]) -> Wt[col][0:128]=bf16 hi, [128:256]=bf16 residual; also zero cnt
__global__ __launch_bounds__(256)
void k_prep_w(const float* __restrict__ w, unsigned short* __restrict__ wt,
              int* __restrict__ cnt, int ncnt)
{
    int idx = blockIdx.x * 256 + threadIdx.x;   // 16384 total
    int col = idx >> 7;
    int k   = idx & 127;
    float v = w[k * F + col];
    unsigned short h = f2bf(v);
    unsigned short lo = f2bf(v - bf2f(h));
    wt[col * 256 + k]       = h;
    wt[col * 256 + 128 + k] = lo;
    for (int i = idx; i < ncnt; i += 64 * 256) cnt[i] = 0;
}

// 64 nodes x 128 cols per 256-thread block; wave w owns cols [w*32, w*32+32)
__global__ __launch_bounds__(256)
void k_gemm_attn(const float* __restrict__ x, const unsigned short* __restrict__ wt,
                 const float* __restrict__ a2, unsigned short* __restrict__ z, int n)
{
    __shared__ __align__(16) unsigned short xls[64 * XS];   // reused as zls[64*ZS] later
    __shared__ float part[4 * 64 * 8];                      // [wave][node][head]
    __shared__ float sarr[64 * 8];                          // [node][head]

    const int t  = threadIdx.x;
    const int l  = t & 63;
    const int w  = t >> 6;
    const int lm = l & 15;
    const int lq = l >> 4;
    const int n0 = blockIdx.x * 64;

    // ---- stage x tile as bf16 hi/lo ----
    #pragma unroll
    for (int i = 0; i < 8; ++i) {
        int idx  = i * 256 + t;
        int node = idx >> 5;
        int k0   = (idx & 31) * 4;
        int gn   = n0 + node;
        float4 v = (gn < n) ? *(const float4*)(x + (long)gn * F + k0)
                            : make_float4(0.f, 0.f, 0.f, 0.f);
        ushort4 h, lo;
        h.x  = f2bf(v.x); h.y  = f2bf(v.y); h.z  = f2bf(v.z); h.w  = f2bf(v.w);
        lo.x = f2bf(v.x - bf2f(h.x));
        lo.y = f2bf(v.y - bf2f(h.y));
        lo.z = f2bf(v.z - bf2f(h.z));
        lo.w = f2bf(v.w - bf2f(h.w));
        *(ushort4*)(&xls[node * XS + k0])       = h;
        *(ushort4*)(&xls[node * XS + 128 + k0]) = lo;
    }
    __syncthreads();

    // ---- MFMA main loop ----
    const int wc = w * 32;
    f32x4 acc[4][2];
    #pragma unroll
    for (int rf = 0; rf < 4; ++rf)
        #pragma unroll
        for (int cf = 0; cf < 2; ++cf)
            acc[rf][cf] = (f32x4){0.f, 0.f, 0.f, 0.f};

    #pragma unroll
    for (int ks = 0; ks < 4; ++ks) {
        const int koff = ks * 32 + lq * 8;
        bf16x8 bh[2], bl[2];
        #pragma unroll
        for (int cf = 0; cf < 2; ++cf) {
            const unsigned short* bp = wt + (wc + cf * 16 + lm) * 256 + koff;
            bh[cf] = *(const bf16x8*)(bp);
            bl[cf] = *(const bf16x8*)(bp + 128);
        }
        bf16x8 ah[4], al[4];
        #pragma unroll
        for (int rf = 0; rf < 4; ++rf) {
            const unsigned short* ap = &xls[(rf * 16 + lm) * XS + koff];
            ah[rf] = *(const bf16x8*)(ap);
            al[rf] = *(const bf16x8*)(ap + 128);
        }
        #pragma unroll
        for (int rf = 0; rf < 4; ++rf)
            #pragma unroll
            for (int cf = 0; cf < 2; ++cf) {
                acc[rf][cf] = __builtin_amdgcn_mfma_f32_16x16x32_bf16(ah[rf], bh[cf], acc[rf][cf], 0, 0, 0);
                acc[rf][cf] = __builtin_amdgcn_mfma_f32_16x16x32_bf16(ah[rf], bl[cf], acc[rf][cf], 0, 0, 0);
                acc[rf][cf] = __builtin_amdgcn_mfma_f32_16x16x32_bf16(al[rf], bh[cf], acc[rf][cf], 0, 0, 0);
            }
    }

    // ---- attn2 partials ----
    const float a20 = a2[wc + lm];
    const float a21 = a2[wc + 16 + lm];
    const int j = l & 7;

    #pragma unroll
    for (int rf = 0; rf < 4; ++rf) {
        #pragma unroll
        for (int r = 0; r < 4; ++r) {
            float pl = acc[rf][0][r] * a20 + acc[rf][1][r] * a21;
            pl += __shfl_xor(pl, 8, 64);
            if ((l & 8) == 0) {
                int node = rf * 16 + lq * 4 + r;
                part[(w * 64 + node) * 8 + j] = pl;
            }
        }
    }
    __syncthreads();   // xls no longer read -> reuse as zls

    unsigned short* zls = xls;

    // ---- s = attn2 + sqrt(attn2^2+1); mask cols into LDS z tile ----
    #pragma unroll
    for (int eo = 0; eo < 2; ++eo) {
        int e    = eo * 256 + t;
        int node = e >> 3;
        int jj   = e & 7;
        float ts = part[(0 * 64 + node) * 8 + jj] + part[(1 * 64 + node) * 8 + jj]
                 + part[(2 * 64 + node) * 8 + jj] + part[(3 * 64 + node) * 8 + jj];
        float s = ts + sqrtf(ts * ts + 1.0f);
        sarr[node * 8 + jj] = s;
        zls[node * ZS + F + jj] = f2bf(s);
    }
    __syncthreads();

    // ---- scale by s[head] into LDS z tile ----
    #pragma unroll
    for (int rf = 0; rf < 4; ++rf) {
        #pragma unroll
        for (int r = 0; r < 4; ++r) {
            int node = rf * 16 + lq * 4 + r;
            float sv = sarr[node * 8 + j];
            #pragma unroll
            for (int cf = 0; cf < 2; ++cf) {
                int c = wc + cf * 16 + lm;
                zls[node * ZS + c] = f2bf(acc[rf][cf][r] * sv);
            }
        }
    }
    __syncthreads();

    // ---- coalesced z write: 64 rows x 17 dwordx4 ----
    #pragma unroll
    for (int i = 0; i < 5; ++i) {
        int idx = i * 256 + t;
        if (idx < 64 * 17) {
            int row = idx / 17;
            int q   = idx - row * 17;
            int gn  = n0 + row;
            if (gn < n) {
                uint4 v = *(const uint4*)(&zls[row * ZS + q * 8]);
                ((uint4*)(z + (long)gn * FP))[q] = v;
            }
        }
    }
}

// hist + per-edge rank (order within row)
__global__ __launch_bounds__(256)
void k_hist(const int* __restrict__ rows, int* __restrict__ cnt,
            int* __restrict__ rank, int E)
{
    int e = blockIdx.x * blockDim.x + threadIdx.x;
    if (e < E) rank[e] = atomicAdd(&cnt[rows[e]], 1);
}

// pass 1: per-1024-elem block reduce -> blockSums
__global__ __launch_bounds__(256)
void k_scan_partial(const int* __restrict__ cnt, int* __restrict__ blockSums, int n)
{
    const int t = threadIdx.x;
    const int base = blockIdx.x * SCAN_ELEMS + t * 4;
    int s = 0;
    #pragma unroll
    for (int k = 0; k < 4; ++k) {
        int i = base + k;
        if (i < n) s += cnt[i];
    }
    #pragma unroll
    for (int off = 32; off >= 1; off >>= 1) s += __shfl_down(s, off, 64);
    __shared__ int ws[4];
    if ((t & 63) == 0) ws[t >> 6] = s;
    __syncthreads();
    if (t == 0) blockSums[blockIdx.x] = ws[0] + ws[1] + ws[2] + ws[3];
}

// pass 2: block offset computed in-kernel from blockSums (nblk <= 64)
__global__ __launch_bounds__(256)
void k_scan_final(const int* __restrict__ cnt, const int* __restrict__ blockSums,
                  int* __restrict__ start, int n, int nblk, int E)
{
    __shared__ int boffs;
    const int t = threadIdx.x;
    const int lane = t & 63;
    const int wv = t >> 6;

    if (t < 64) {
        int v = (t < nblk && t < blockIdx.x) ? blockSums[t] : 0;
        #pragma unroll
        for (int off = 32; off >= 1; off >>= 1) v += __shfl_down(v, off, 64);
        if (t == 0) boffs = v;
    }

    const int base = blockIdx.x * SCAN_ELEMS + t * 4;
    int v[4];
    int sum4 = 0;
    #pragma unroll
    for (int k = 0; k < 4; ++k) {
        int i = base + k;
        v[k] = (i < n) ? cnt[i] : 0;
        sum4 += v[k];
    }

    int incl = sum4;
    #pragma unroll
    for (int off = 1; off < 64; off <<= 1) {
        int u = __shfl_up(incl, off, 64);
        if (lane >= off) incl += u;
    }

    __shared__ int waveSums[4];
    if (lane == 63) waveSums[wv] = incl;
    __syncthreads();
    if (t == 0) {
        int r = 0;
        #pragma unroll
        for (int w2 = 0; w2 < 4; ++w2) { int tmp = waveSums[w2]; waveSums[w2] = r; r += tmp; }
    }
    __syncthreads();

    int run = boffs + waveSums[wv] + (incl - sum4);
    #pragma unroll
    for (int k = 0; k < 4; ++k) {
        int i = base + k;
        if (i < n) start[i] = run;
        run += v[k];
        if (i == n - 1) start[n] = E;   // CSR end pointer
    }
}

// atomic-free scatter: pos = start[row] + rank
__global__ __launch_bounds__(256)
void k_scatter(const int* __restrict__ rows, const int* __restrict__ cols,
               const float* __restrict__ vals, const int* __restrict__ start,
               const int* __restrict__ rank, int2* __restrict__ ce, int E)
{
    int e = blockIdx.x * blockDim.x + threadIdx.x;
    if (e >= E) return;
    int pos = start[rows[e]] + rank[e];
    ce[pos] = make_int2(cols[e], __float_as_int(vals[e]));
}

// one 16-lane group per destination row (4 rows/wave); lane owns 8 bf16 cols
__global__ __launch_bounds__(256)
void k_spmm_pull(const int* __restrict__ start, const int2* __restrict__ ce,
                 const unsigned short* __restrict__ z, const float* __restrict__ bias,
                 float* __restrict__ out, int n)
{
    const int grp  = (blockIdx.x * blockDim.x + threadIdx.x) >> 4;   // row
    const int lane = threadIdx.x & 63;
    const int c16  = lane & 15;
    if (grp >= n) return;

    const int mq = c16 & 3;
    const int s0  = start[grp];
    const int end = start[grp + 1];

    float az[8];
    #pragma unroll
    for (int k = 0; k < 8; ++k) az[k] = 0.f;
    float am0 = 0.f, am1 = 0.f;

    int e = s0;
    for (; e + 1 < end; e += 2) {          // 2 edges in flight per group
        int2 p0 = ce[e];
        int2 p1 = ce[e + 1];
        const unsigned short* b0 = z + (long)p0.x * FP;
        const unsigned short* b1 = z + (long)p1.x * FP;
        uint4 d0 = *(const uint4*)(b0 + 8 * c16);
        unsigned int m0 = *((const unsigned int*)(b0 + F) + mq);
        uint4 d1 = *(const uint4*)(b1 + 8 * c16);
        unsigned int m1 = *((const unsigned int*)(b1 + F) + mq);
        float v0 = __int_as_float(p0.y);
        float v1 = __int_as_float(p1.y);

        az[0] = fmaf(v0, bf_lo(d0.x), az[0]);  az[1] = fmaf(v0, bf_hi(d0.x), az[1]);
        az[2] = fmaf(v0, bf_lo(d0.y), az[2]);  az[3] = fmaf(v0, bf_hi(d0.y), az[3]);
        az[4] = fmaf(v0, bf_lo(d0.z), az[4]);  az[5] = fmaf(v0, bf_hi(d0.z), az[5]);
        az[6] = fmaf(v0, bf_lo(d0.w), az[6]);  az[7] = fmaf(v0, bf_hi(d0.w), az[7]);
        am0   = fmaf(v0, bf_lo(m0), am0);      am1   = fmaf(v0, bf_hi(m0), am1);

        az[0] = fmaf(v1, bf_lo(d1.x), az[0]);  az[1] = fmaf(v1, bf_hi(d1.x), az[1]);
        az[2] = fmaf(v1, bf_lo(d1.y), az[2]);  az[3] = fmaf(v1, bf_hi(d1.y), az[3]);
        az[4] = fmaf(v1, bf_lo(d1.z), az[4]);  az[5] = fmaf(v1, bf_hi(d1.z), az[5]);
        az[6] = fmaf(v1, bf_lo(d1.w), az[6]);  az[7] = fmaf(v1, bf_hi(d1.w), az[7]);
        am0   = fmaf(v1, bf_lo(m1), am0);      am1   = fmaf(v1, bf_hi(m1), am1);
    }
    if (e < end) {
        int2 p0 = ce[e];
        const unsigned short* b0 = z + (long)p0.x * FP;
        uint4 d0 = *(const uint4*)(b0 + 8 * c16);
        unsigned int m0 = *((const unsigned int*)(b0 + F) + mq);
        float v0 = __int_as_float(p0.y);
        az[0] = fmaf(v0, bf_lo(d0.x), az[0]);  az[1] = fmaf(v0, bf_hi(d0.x), az[1]);
        az[2] = fmaf(v0, bf_lo(d0.y), az[2]);  az[3] = fmaf(v0, bf_hi(d0.y), az[3]);
        az[4] = fmaf(v0, bf_lo(d0.z), az[4]);  az[5] = fmaf(v0, bf_hi(d0.z), az[5]);
        az[6] = fmaf(v0, bf_lo(d0.w), az[6]);  az[7] = fmaf(v0, bf_hi(d0.w), az[7]);
        am0   = fmaf(v0, bf_lo(m0), am0);      am1   = fmaf(v0, bf_hi(m0), am1);
    }

    // denominators: head h lives in lane (groupbase + h/2), am0=even head, am1=odd
    const int gb = lane & 48;
    float den[8];
    den[0] = __shfl(am0, gb + 0, 64);  den[1] = __shfl(am1, gb + 0, 64);
    den[2] = __shfl(am0, gb + 1, 64);  den[3] = __shfl(am1, gb + 1, 64);
    den[4] = __shfl(am0, gb + 2, 64);  den[5] = __shfl(am1, gb + 2, 64);
    den[6] = __shfl(am0, gb + 3, 64);  den[7] = __shfl(am1, gb + 3, 64);

    const float* bp = bias + 8 * c16;   // col 8*c16+k has head k
    float4 b0v = *(const float4*)(bp);
    float4 b1v = *(const float4*)(bp + 4);
    float4 o0, o1;
    o0.x = az[0] / (den[0] + 1e-9f) + b0v.x;
    o0.y = az[1] / (den[1] + 1e-9f) + b0v.y;
    o0.z = az[2] / (den[2] + 1e-9f) + b0v.z;
    o0.w = az[3] / (den[3] + 1e-9f) + b0v.w;
    o1.x = az[4] / (den[4] + 1e-9f) + b1v.x;
    o1.y = az[5] / (den[5] + 1e-9f) + b1v.y;
    o1.z = az[6] / (den[6] + 1e-9f) + b1v.z;
    o1.w = az[7] / (den[7] + 1e-9f) + b1v.w;
    float* op = out + (long)grp * F + 8 * c16;
    *(float4*)(op)     = o0;
    *(float4*)(op + 4) = o1;
}

extern "C" void kernel_launch(void* const* d_in, const int* in_sizes, int n_in,
                              void* d_out, int out_size, void* d_ws, size_t ws_size,
                              hipStream_t stream)
{
    const float* x    = (const float*)d_in[0];
    const int*   ei   = (const int*)d_in[1];
    const float* vals = (const float*)d_in[2];
    const float* w    = (const float*)d_in[3];
    const float* bias = (const float*)d_in[4];
    const float* a2   = (const float*)d_in[5];
    float* out = (float*)d_out;

    const int N = in_sizes[0] / F;
    const int E = in_sizes[2];
    const int* rows = ei;
    const int* cols = ei + E;

    const int nblk = (N + SCAN_ELEMS - 1) / SCAN_ELEMS;   // 49 (<=64 required)

    char* p = (char*)d_ws;
    unsigned short* z  = (unsigned short*)p;  p += (((size_t)N * FP * sizeof(unsigned short) + 255) & ~255ull);
    unsigned short* wt = (unsigned short*)p;  p += 128 * 256 * sizeof(unsigned short);
    int*   cnt      = (int*)p;    p += ((size_t)N + 64) * sizeof(int);
    int*   start    = (int*)p;    p += ((size_t)N + 64) * sizeof(int);
    int*   blockSums= (int*)p;    p += 512 * sizeof(int);
    int*   rank     = (int*)p;    p += (size_t)E * sizeof(int);
    int2*  ce       = (int2*)p;

    k_prep_w<<<dim3(64), dim3(256), 0, stream>>>(w, wt, cnt, N);

    dim3 b1(256), g1((N + 63) / 64);
    k_gemm_attn<<<g1, b1, 0, stream>>>(x, wt, a2, z, N);

    k_hist<<<dim3((E + 255) / 256), dim3(256), 0, stream>>>(rows, cnt, rank, E);

    k_scan_partial<<<dim3(nblk), dim3(256), 0, stream>>>(cnt, blockSums, N);
    k_scan_final<<<dim3(nblk), dim3(256), 0, stream>>>(cnt, blockSums, start, N, nblk, E);

    k_scatter<<<dim3((E + 255) / 256), dim3(256), 0, stream>>>(rows, cols, vals, start, rank, ce, E);

    dim3 b5(256), g5(((size_t)N * 16 + 255) / 256);
    k_spmm_pull<<<g5, b5, 0, stream>>>(start, ce, z, bias, out, N);
}

// Round 9
// 93.008 us; speedup vs baseline: 11.2470x; 1.0372x over previous
//
#include <hip/hip_runtime.h>
#include <hip/hip_bf16.h>

// SGAT layer, pull-based, bf16 z, MFMA split-bf16 GEMM, group-per-row SpMM.
//   z = [ (x@W) * s ; s ]  with s = attn2 + sqrt(attn2^2+1)   (N x 136, bf16)
//   x@W via 3-term split-bf16 MFMA (~fp32 accuracy)
//   CSR build: hist+rank fused into gemm tail; one-kernel lookback scan;
//   atomic-free scatter. 16-lane-group-per-row gather, 4 edges in flight,
//   fused normalize/bias epilogue. 5 dispatches total.

#define F 128      // F_OUT * H
#define FP 136     // F_OUT*H + H
#define NH 8
#define SCAN_ELEMS 1024
#define XS 264     // x staging row stride (ushorts): hi|lo, 16B-aligned
#define ZS 144     // z staging row stride (ushorts): 288B, 16B-aligned, bank-spread

typedef __attribute__((ext_vector_type(8))) short bf16x8;
typedef __attribute__((ext_vector_type(4))) float f32x4;

static __device__ __forceinline__ unsigned short f2bf(float f) {
    __hip_bfloat16 h = __float2bfloat16(f);   // RNE
    return *(unsigned short*)&h;
}
static __device__ __forceinline__ float bf2f(unsigned short u) {
    return __uint_as_float((unsigned int)u << 16);
}
static __device__ __forceinline__ float bf_lo(unsigned int u) { return __uint_as_float(u << 16); }
static __device__ __forceinline__ float bf_hi(unsigned int u) { return __uint_as_float(u & 0xFFFF0000u); }

// W(128x128 fp32 [k][c]) -> Wt[col][0:128]=bf16 hi, [128:256]=bf16 residual.
// Also zeroes cnt and the scan flag array (required fresh every call).
__global__ __launch_bounds__(256)
void k_prep_w(const float* __restrict__ w, unsigned short* __restrict__ wt,
              int* __restrict__ cnt, int ncnt, int* __restrict__ flagsum)
{
    int idx = blockIdx.x * 256 + threadIdx.x;   // 16384 total
    int col = idx >> 7;
    int k   = idx & 127;
    float v = w[k * F + col];
    unsigned short h = f2bf(v);
    unsigned short lo = f2bf(v - bf2f(h));
    wt[col * 256 + k]       = h;
    wt[col * 256 + 128 + k] = lo;
    if (idx < 64) flagsum[idx] = 0;
    for (int i = idx; i < ncnt; i += 64 * 256) cnt[i] = 0;
}

// 64 nodes x 128 cols per 256-thread block; wave w owns cols [w*32, w*32+32).
// Tail: grid-stride edge histogram + rank (cnt pre-zeroed by k_prep_w).
__global__ __launch_bounds__(256)
void k_gemm_attn(const float* __restrict__ x, const unsigned short* __restrict__ wt,
                 const float* __restrict__ a2, unsigned short* __restrict__ z, int n,
                 const int* __restrict__ rows, int* __restrict__ cnt,
                 int* __restrict__ rank, int E)
{
    __shared__ __align__(16) unsigned short xls[64 * XS];   // reused as zls later
    __shared__ float part[4 * 64 * 8];                      // [wave][node][head]
    __shared__ float sarr[64 * 8];                          // [node][head]

    const int t  = threadIdx.x;
    const int l  = t & 63;
    const int w  = t >> 6;
    const int lm = l & 15;
    const int lq = l >> 4;
    const int n0 = blockIdx.x * 64;

    // ---- stage x tile as bf16 hi/lo ----
    #pragma unroll
    for (int i = 0; i < 8; ++i) {
        int idx  = i * 256 + t;
        int node = idx >> 5;
        int k0   = (idx & 31) * 4;
        int gn   = n0 + node;
        float4 v = (gn < n) ? *(const float4*)(x + (long)gn * F + k0)
                            : make_float4(0.f, 0.f, 0.f, 0.f);
        ushort4 h, lo;
        h.x  = f2bf(v.x); h.y  = f2bf(v.y); h.z  = f2bf(v.z); h.w  = f2bf(v.w);
        lo.x = f2bf(v.x - bf2f(h.x));
        lo.y = f2bf(v.y - bf2f(h.y));
        lo.z = f2bf(v.z - bf2f(h.z));
        lo.w = f2bf(v.w - bf2f(h.w));
        *(ushort4*)(&xls[node * XS + k0])       = h;
        *(ushort4*)(&xls[node * XS + 128 + k0]) = lo;
    }
    __syncthreads();

    // ---- MFMA main loop ----
    const int wc = w * 32;
    f32x4 acc[4][2];
    #pragma unroll
    for (int rf = 0; rf < 4; ++rf)
        #pragma unroll
        for (int cf = 0; cf < 2; ++cf)
            acc[rf][cf] = (f32x4){0.f, 0.f, 0.f, 0.f};

    #pragma unroll
    for (int ks = 0; ks < 4; ++ks) {
        const int koff = ks * 32 + lq * 8;
        bf16x8 bh[2], bl[2];
        #pragma unroll
        for (int cf = 0; cf < 2; ++cf) {
            const unsigned short* bp = wt + (wc + cf * 16 + lm) * 256 + koff;
            bh[cf] = *(const bf16x8*)(bp);
            bl[cf] = *(const bf16x8*)(bp + 128);
        }
        bf16x8 ah[4], al[4];
        #pragma unroll
        for (int rf = 0; rf < 4; ++rf) {
            const unsigned short* ap = &xls[(rf * 16 + lm) * XS + koff];
            ah[rf] = *(const bf16x8*)(ap);
            al[rf] = *(const bf16x8*)(ap + 128);
        }
        #pragma unroll
        for (int rf = 0; rf < 4; ++rf)
            #pragma unroll
            for (int cf = 0; cf < 2; ++cf) {
                acc[rf][cf] = __builtin_amdgcn_mfma_f32_16x16x32_bf16(ah[rf], bh[cf], acc[rf][cf], 0, 0, 0);
                acc[rf][cf] = __builtin_amdgcn_mfma_f32_16x16x32_bf16(ah[rf], bl[cf], acc[rf][cf], 0, 0, 0);
                acc[rf][cf] = __builtin_amdgcn_mfma_f32_16x16x32_bf16(al[rf], bh[cf], acc[rf][cf], 0, 0, 0);
            }
    }

    // ---- attn2 partials ----
    const float a20 = a2[wc + lm];
    const float a21 = a2[wc + 16 + lm];
    const int j = l & 7;

    #pragma unroll
    for (int rf = 0; rf < 4; ++rf) {
        #pragma unroll
        for (int r = 0; r < 4; ++r) {
            float pl = acc[rf][0][r] * a20 + acc[rf][1][r] * a21;
            pl += __shfl_xor(pl, 8, 64);
            if ((l & 8) == 0) {
                int node = rf * 16 + lq * 4 + r;
                part[(w * 64 + node) * 8 + j] = pl;
            }
        }
    }
    __syncthreads();   // xls no longer read -> reuse as zls

    unsigned short* zls = xls;

    // ---- s = attn2 + sqrt(attn2^2+1); mask cols into LDS z tile ----
    #pragma unroll
    for (int eo = 0; eo < 2; ++eo) {
        int e    = eo * 256 + t;
        int node = e >> 3;
        int jj   = e & 7;
        float ts = part[(0 * 64 + node) * 8 + jj] + part[(1 * 64 + node) * 8 + jj]
                 + part[(2 * 64 + node) * 8 + jj] + part[(3 * 64 + node) * 8 + jj];
        float s = ts + sqrtf(ts * ts + 1.0f);
        sarr[node * 8 + jj] = s;
        zls[node * ZS + F + jj] = f2bf(s);
    }
    __syncthreads();

    // ---- scale by s[head] into LDS z tile ----
    #pragma unroll
    for (int rf = 0; rf < 4; ++rf) {
        #pragma unroll
        for (int r = 0; r < 4; ++r) {
            int node = rf * 16 + lq * 4 + r;
            float sv = sarr[node * 8 + j];
            #pragma unroll
            for (int cf = 0; cf < 2; ++cf) {
                int c = wc + cf * 16 + lm;
                zls[node * ZS + c] = f2bf(acc[rf][cf][r] * sv);
            }
        }
    }
    __syncthreads();

    // ---- coalesced z write: 64 rows x 17 dwordx4 ----
    #pragma unroll
    for (int i = 0; i < 5; ++i) {
        int idx = i * 256 + t;
        if (idx < 64 * 17) {
            int row = idx / 17;
            int q   = idx - row * 17;
            int gn  = n0 + row;
            if (gn < n) {
                uint4 v = *(const uint4*)(&zls[row * ZS + q * 8]);
                ((uint4*)(z + (long)gn * FP))[q] = v;
            }
        }
    }

    // ---- fused edge histogram + rank (hidden under other waves' work) ----
    const int gtid = blockIdx.x * 256 + t;
    const int nth  = gridDim.x * 256;
    for (int e = gtid; e < E; e += nth)
        rank[e] = atomicAdd(&cnt[rows[e]], 1);
}

// one-kernel exclusive scan via decoupled lookback (nblk <= 64 blocks, all resident)
__global__ __launch_bounds__(256)
void k_scan_one(const int* __restrict__ cnt, int* __restrict__ flagsum,
                int* __restrict__ start, int n, int E)
{
    const int b = blockIdx.x;
    const int t = threadIdx.x;
    const int lane = t & 63;
    const int wv = t >> 6;
    const int base = b * SCAN_ELEMS + t * 4;

    int v[4];
    int sum4 = 0;
    #pragma unroll
    for (int k = 0; k < 4; ++k) {
        int i = base + k;
        v[k] = (i < n) ? cnt[i] : 0;
        sum4 += v[k];
    }

    int incl = sum4;
    #pragma unroll
    for (int off = 1; off < 64; off <<= 1) {
        int u = __shfl_up(incl, off, 64);
        if (lane >= off) incl += u;
    }

    __shared__ int waveSums[4];
    __shared__ int boffs_sh;
    if (lane == 63) waveSums[wv] = incl;
    __syncthreads();
    if (t == 0) {
        int r = 0;
        #pragma unroll
        for (int w2 = 0; w2 < 4; ++w2) { int tmp = waveSums[w2]; waveSums[w2] = r; r += tmp; }
        atomicExch(&flagsum[b], r + 1);          // publish packed block total
    }

    if (t < 64) {                                 // lookback over predecessors
        int acc = 0;
        for (int i = lane; i < b; i += 64) {
            int f;
            while ((f = atomicAdd(&flagsum[i], 0)) == 0) { }
            acc += f - 1;
        }
        #pragma unroll
        for (int off = 32; off >= 1; off >>= 1) acc += __shfl_down(acc, off, 64);
        if (t == 0) boffs_sh = acc;
    }
    __syncthreads();

    int run = boffs_sh + waveSums[wv] + (incl - sum4);
    #pragma unroll
    for (int k = 0; k < 4; ++k) {
        int i = base + k;
        if (i < n) start[i] = run;
        run += v[k];
        if (i == n - 1) start[n] = E;   // CSR end pointer
    }
}

// atomic-free scatter: pos = start[row] + rank
__global__ __launch_bounds__(256)
void k_scatter(const int* __restrict__ rows, const int* __restrict__ cols,
               const float* __restrict__ vals, const int* __restrict__ start,
               const int* __restrict__ rank, int2* __restrict__ ce, int E)
{
    int e = blockIdx.x * blockDim.x + threadIdx.x;
    if (e >= E) return;
    int pos = start[rows[e]] + rank[e];
    ce[pos] = make_int2(cols[e], __float_as_int(vals[e]));
}

// one 16-lane group per destination row (4 rows/wave); lane owns 8 bf16 cols;
// 4 edges in flight per group
__global__ __launch_bounds__(256)
void k_spmm_pull(const int* __restrict__ start, const int2* __restrict__ ce,
                 const unsigned short* __restrict__ z, const float* __restrict__ bias,
                 float* __restrict__ out, int n)
{
    const int grp  = (blockIdx.x * blockDim.x + threadIdx.x) >> 4;   // row
    const int lane = threadIdx.x & 63;
    const int c16  = lane & 15;
    if (grp >= n) return;

    const int mq  = c16 & 3;
    const int s0  = start[grp];
    const int end = start[grp + 1];

    float az[8];
    #pragma unroll
    for (int k = 0; k < 8; ++k) az[k] = 0.f;
    float am0 = 0.f, am1 = 0.f;

    for (int e = s0; e < end; e += 4) {
        int e1 = (e + 1 < end) ? e + 1 : end - 1;
        int e2 = (e + 2 < end) ? e + 2 : end - 1;
        int e3 = (e + 3 < end) ? e + 3 : end - 1;
        int2 p0 = ce[e];
        int2 p1 = ce[e1];
        int2 p2 = ce[e2];
        int2 p3 = ce[e3];
        float v0 = __int_as_float(p0.y);
        float v1 = (e + 1 < end) ? __int_as_float(p1.y) : 0.f;
        float v2 = (e + 2 < end) ? __int_as_float(p2.y) : 0.f;
        float v3 = (e + 3 < end) ? __int_as_float(p3.y) : 0.f;
        const unsigned short* b0 = z + (long)p0.x * FP;
        const unsigned short* b1 = z + (long)p1.x * FP;
        const unsigned short* b2 = z + (long)p2.x * FP;
        const unsigned short* b3 = z + (long)p3.x * FP;
        uint4 d0 = *(const uint4*)(b0 + 8 * c16);
        uint4 d1 = *(const uint4*)(b1 + 8 * c16);
        uint4 d2 = *(const uint4*)(b2 + 8 * c16);
        uint4 d3 = *(const uint4*)(b3 + 8 * c16);
        unsigned int m0 = *((const unsigned int*)(b0 + F) + mq);
        unsigned int m1 = *((const unsigned int*)(b1 + F) + mq);
        unsigned int m2 = *((const unsigned int*)(b2 + F) + mq);
        unsigned int m3 = *((const unsigned int*)(b3 + F) + mq);

        az[0] = fmaf(v0, bf_lo(d0.x), az[0]);  az[1] = fmaf(v0, bf_hi(d0.x), az[1]);
        az[2] = fmaf(v0, bf_lo(d0.y), az[2]);  az[3] = fmaf(v0, bf_hi(d0.y), az[3]);
        az[4] = fmaf(v0, bf_lo(d0.z), az[4]);  az[5] = fmaf(v0, bf_hi(d0.z), az[5]);
        az[6] = fmaf(v0, bf_lo(d0.w), az[6]);  az[7] = fmaf(v0, bf_hi(d0.w), az[7]);
        am0   = fmaf(v0, bf_lo(m0), am0);      am1   = fmaf(v0, bf_hi(m0), am1);

        az[0] = fmaf(v1, bf_lo(d1.x), az[0]);  az[1] = fmaf(v1, bf_hi(d1.x), az[1]);
        az[2] = fmaf(v1, bf_lo(d1.y), az[2]);  az[3] = fmaf(v1, bf_hi(d1.y), az[3]);
        az[4] = fmaf(v1, bf_lo(d1.z), az[4]);  az[5] = fmaf(v1, bf_hi(d1.z), az[5]);
        az[6] = fmaf(v1, bf_lo(d1.w), az[6]);  az[7] = fmaf(v1, bf_hi(d1.w), az[7]);
        am0   = fmaf(v1, bf_lo(m1), am0);      am1   = fmaf(v1, bf_hi(m1), am1);

        az[0] = fmaf(v2, bf_lo(d2.x), az[0]);  az[1] = fmaf(v2, bf_hi(d2.x), az[1]);
        az[2] = fmaf(v2, bf_lo(d2.y), az[2]);  az[3] = fmaf(v2, bf_hi(d2.y), az[3]);
        az[4] = fmaf(v2, bf_lo(d2.z), az[4]);  az[5] = fmaf(v2, bf_hi(d2.z), az[5]);
        az[6] = fmaf(v2, bf_lo(d2.w), az[6]);  az[7] = fmaf(v2, bf_hi(d2.w), az[7]);
        am0   = fmaf(v2, bf_lo(m2), am0);      am1   = fmaf(v2, bf_hi(m2), am1);

        az[0] = fmaf(v3, bf_lo(d3.x), az[0]);  az[1] = fmaf(v3, bf_hi(d3.x), az[1]);
        az[2] = fmaf(v3, bf_lo(d3.y), az[2]);  az[3] = fmaf(v3, bf_hi(d3.y), az[3]);
        az[4] = fmaf(v3, bf_lo(d3.z), az[4]);  az[5] = fmaf(v3, bf_hi(d3.z), az[5]);
        az[6] = fmaf(v3, bf_lo(d3.w), az[6]);  az[7] = fmaf(v3, bf_hi(d3.w), az[7]);
        am0   = fmaf(v3, bf_lo(m3), am0);      am1   = fmaf(v3, bf_hi(m3), am1);
    }

    // denominators: lane gb+i holds heads 2i (am0) and 2i+1 (am1)
    const int gb = lane & 48;
    float den[8];
    den[0] = __shfl(am0, gb + 0, 64);  den[1] = __shfl(am1, gb + 0, 64);
    den[2] = __shfl(am0, gb + 1, 64);  den[3] = __shfl(am1, gb + 1, 64);
    den[4] = __shfl(am0, gb + 2, 64);  den[5] = __shfl(am1, gb + 2, 64);
    den[6] = __shfl(am0, gb + 3, 64);  den[7] = __shfl(am1, gb + 3, 64);

    const float* bp = bias + 8 * c16;   // col 8*c16+k has head k
    float4 b0v = *(const float4*)(bp);
    float4 b1v = *(const float4*)(bp + 4);
    float4 o0, o1;
    o0.x = az[0] / (den[0] + 1e-9f) + b0v.x;
    o0.y = az[1] / (den[1] + 1e-9f) + b0v.y;
    o0.z = az[2] / (den[2] + 1e-9f) + b0v.z;
    o0.w = az[3] / (den[3] + 1e-9f) + b0v.w;
    o1.x = az[4] / (den[4] + 1e-9f) + b1v.x;
    o1.y = az[5] / (den[5] + 1e-9f) + b1v.y;
    o1.z = az[6] / (den[6] + 1e-9f) + b1v.z;
    o1.w = az[7] / (den[7] + 1e-9f) + b1v.w;
    float* op = out + (long)grp * F + 8 * c16;
    *(float4*)(op)     = o0;
    *(float4*)(op + 4) = o1;
}

extern "C" void kernel_launch(void* const* d_in, const int* in_sizes, int n_in,
                              void* d_out, int out_size, void* d_ws, size_t ws_size,
                              hipStream_t stream)
{
    const float* x    = (const float*)d_in[0];
    const int*   ei   = (const int*)d_in[1];
    const float* vals = (const float*)d_in[2];
    const float* w    = (const float*)d_in[3];
    const float* bias = (const float*)d_in[4];
    const float* a2   = (const float*)d_in[5];
    float* out = (float*)d_out;

    const int N = in_sizes[0] / F;
    const int E = in_sizes[2];
    const int* rows = ei;
    const int* cols = ei + E;

    const int nblk = (N + SCAN_ELEMS - 1) / SCAN_ELEMS;   // 49 (<=64 required)

    char* p = (char*)d_ws;
    unsigned short* z  = (unsigned short*)p;  p += (((size_t)N * FP * sizeof(unsigned short) + 255) & ~255ull);
    unsigned short* wt = (unsigned short*)p;  p += 128 * 256 * sizeof(unsigned short);
    int*   cnt      = (int*)p;    p += ((size_t)N + 64) * sizeof(int);
    int*   start    = (int*)p;    p += ((size_t)N + 64) * sizeof(int);
    int*   flagsum  = (int*)p;    p += 64 * sizeof(int);
    int*   rank     = (int*)p;    p += (size_t)E * sizeof(int);
    int2*  ce       = (int2*)p;

    k_prep_w<<<dim3(64), dim3(256), 0, stream>>>(w, wt, cnt, N, flagsum);

    dim3 b1(256), g1((N + 63) / 64);
    k_gemm_attn<<<g1, b1, 0, stream>>>(x, wt, a2, z, N, rows, cnt, rank, E);

    k_scan_one<<<dim3(nblk), dim3(256), 0, stream>>>(cnt, flagsum, start, N, E);

    k_scatter<<<dim3((E + 255) / 256), dim3(256), 0, stream>>>(rows, cols, vals, start, rank, ce, E);

    dim3 b5(256), g5(((size_t)N * 16 + 255) / 256);
    k_spmm_pull<<<g5, b5, 0, stream>>>(start, ce, z, bias, out, N);
}